// Round 8
// baseline (332.429 us; speedup 1.0000x reference)
//
#include <hip/hip_runtime.h>

#define NN 20000
#define EE 320000
#define RATIO_F 0.18257418583505536f   // 1/sqrt(30)
#define EPS_F 1e-6f
#define SCALE_D4 0.35355339059327373f  // 64^-0.25
#define NCH 157                        // ceil(20000/128) k3 chunks

typedef _Float16 f16x8 __attribute__((ext_vector_type(8)));
typedef _Float16 f16x4 __attribute__((ext_vector_type(4)));
typedef float f32x4 __attribute__((ext_vector_type(4)));

__device__ __forceinline__ unsigned fenc(float x) {
  unsigned u = __float_as_uint(x);
  return (u & 0x80000000u) ? ~u : (u | 0x80000000u);
}
__device__ __forceinline__ float fdec(unsigned u) {
  return (u & 0x80000000u) ? __uint_as_float(u & 0x7FFFFFFFu) : __uint_as_float(~u);
}
__device__ __forceinline__ void fma4(float* a, float s, float4 b) {
  a[0] = fmaf(s, b.x, a[0]);
  a[1] = fmaf(s, b.y, a[1]);
  a[2] = fmaf(s, b.z, a[2]);
  a[3] = fmaf(s, b.w, a[3]);
}
// async global->LDS, 16B per lane; LDS dest must be wave-uniform base + lane*16
__device__ __forceinline__ void gload16(const void* g, void* l) {
  __builtin_amdgcn_global_load_lds(
      (const __attribute__((address_space(1))) unsigned int*)g,
      (__attribute__((address_space(3))) unsigned int*)l, 16, 0, 0);
}

// =====================================================================
// K0: build fused weight plane (f16) in MFMA B-fragment order.
// Columns (1024 = 64 cts): [0,256)=q  [256,512)=k  [512,768)=v
//   xd_q head h = cts 48+2h,49+2h (m<30 valid); xd_k head h = cts 56+2h,57+2h
// Fragment fi = ct*8+kt (512 f16); lane l=(g*16+cl), elem j holds
// W[k=32*kt+8*g+j][col=ct*16+cl].
// =====================================================================
__global__ __launch_bounds__(256)
void k0_build(const float* __restrict__ Wq, const float* __restrict__ Wk,
              const float* __restrict__ Wv, const float* __restrict__ bq,
              const float* __restrict__ bk, const float* __restrict__ bv,
              const float* __restrict__ proj, const float* __restrict__ tau,
              _Float16* __restrict__ Wf, float* __restrict__ bbig) {
  const int col = blockIdx.x;
  const int i = threadIdx.x;   // k index
  const float s = rsqrtf(tau[0]) * SCALE_D4;
  float val = 0.f, bias = 0.f;
  if (col < 256) {
    val = Wq[col * 256 + i]; bias = bq[col];
  } else if (col < 512) {
    const int c = col - 256;
    val = Wk[c * 256 + i]; bias = bk[c];
  } else if (col < 768) {
    const int c = col - 512;
    val = Wv[c * 256 + i]; bias = bv[c];
  } else {
    const int rr = col - 768;
    const int grp = rr >> 7;             // 0 = q, 1 = k
    const int h = (rr >> 5) & 3, m = rr & 31;
    if (m < 30) {
      const float* W = grp ? Wk : Wq;
      const float* bb = grp ? bk : bq;
      float a = 0.f, ba = 0.f;
#pragma unroll 8
      for (int d = 0; d < 64; ++d) {
        const float pr = proj[m * 64 + d];
        a  = fmaf(pr, W[(h * 64 + d) * 256 + i], a);
        ba = fmaf(pr, bb[h * 64 + d], ba);
      }
      val = s * a; bias = s * ba;
    }
  }
  const int kt = i >> 5, gg = (i >> 3) & 3, j = i & 7;
  const int lane = gg * 16 + (col & 15);
  const size_t off = (size_t)((col >> 4) * 8 + kt) * 512 + lane * 8 + j;
  Wf[off] = (_Float16)val;
  if (i == 0) bbig[col] = bias;
}

// ---- convert 4 kt worth of raw float4 pairs -> f16 hi + f16 residual ----
__device__ __forceinline__ void cvt_half(const float4* raw, f16x8* Ah, f16x8* Al) {
#pragma unroll
  for (int kt = 0; kt < 4; ++kt) {
    const float ff[8] = {raw[kt*2].x, raw[kt*2].y, raw[kt*2].z, raw[kt*2].w,
                         raw[kt*2+1].x, raw[kt*2+1].y, raw[kt*2+1].z, raw[kt*2+1].w};
    union { _Float16 h[8]; f16x8 v; } hu, lu;
#pragma unroll
    for (int j = 0; j < 8; ++j) {
      const _Float16 hb = (_Float16)ff[j];
      hu.h[j] = hb;
      lu.h[j] = (_Float16)(ff[j] - (float)hb);
    }
    Ah[kt] = hu.v; Al[kt] = lu.v;
  }
}

// ---- 4 kt x NCT cts of MFMA, hi+lo merged into one acc per ct ----
template <int NCT>
__device__ __forceinline__ void mfma_half(const _Float16* __restrict__ blds,
                                          int ktbase, const f16x8* Ah,
                                          const f16x8* Al, int lane, f32x4* acc) {
#pragma unroll
  for (int kt = 0; kt < 4; ++kt) {
#pragma unroll
    for (int s = 0; s < NCT; ++s) {
      const f16x8 b = *(const f16x8*)&blds[s * 4096 + (ktbase + kt) * 512 + lane * 8];
      acc[s] = __builtin_amdgcn_mfma_f32_16x16x32_f16(Ah[kt], b, acc[s], 0, 0, 0);
      acc[s] = __builtin_amdgcn_mfma_f32_16x16x32_f16(Al[kt], b, acc[s], 0, 0, 0);
    }
  }
}

// =====================================================================
// K1: grid (157, 12) x 512 thr (8 waves x 16 rows). ONE barrier/block.
//  y<8: slice (qk = y>>2, head = y&3): 4 proj cts + 2 xd cts (48 KB LDS).
//       diag + row-max + exp all wave-local registers. No restage.
//  y>=8: v quarter (4 cts, 32 KB of the 48 used).
// Pipeline: [B gloads + A-half0 loads + cvt] -> barrier ->
//           [A-half1 issue -> half0 MFMA -> cvt -> half1 MFMA] -> epilogue.
// =====================================================================
__global__ __launch_bounds__(512, 4)
void k1_all(const float* __restrict__ feat, const float* __restrict__ zin,
            const _Float16* __restrict__ Wf, const float* __restrict__ bbig,
            const float* __restrict__ tau,
            float* __restrict__ qp, float* __restrict__ kbuf,
            _Float16* __restrict__ vh, unsigned* __restrict__ kmaxU) {
  __shared__ __align__(16) _Float16 blds[6 * 4096];   // 48 KB
  const int t = threadIdx.x;
  const int wid = t >> 6, lane = t & 63;
  const int g = lane >> 4, cl = lane & 15;
  const int y = blockIdx.y;
  const int rbase = blockIdx.x * 128 + wid * 16;
  int arow = rbase + cl; if (arow > NN - 1) arow = NN - 1;

  const int isv = (y >= 8);
  const int h = y & 3, qk = (y >> 2) & 1;
  int cts[6];
  if (!isv) {
    const int cb = (qk ? 16 : 0) + h * 4;
    const int xb = (qk ? 56 : 48) + 2 * h;
    cts[0] = cb; cts[1] = cb + 1; cts[2] = cb + 2; cts[3] = cb + 3;
    cts[4] = xb; cts[5] = xb + 1;
  } else {
    const int cb = 32 + (y - 8) * 4;
    cts[0] = cb; cts[1] = cb + 1; cts[2] = cb + 2; cts[3] = cb + 3;
    cts[4] = cb; cts[5] = cb;
  }

  // ---- stage B (async) ----
  if (!isv) {
#pragma unroll
    for (int s = 0; s < 6; ++s)
      gload16(Wf + (size_t)cts[s] * 4096 + t * 8, &blds[(s * 512 + t) * 8]);
  } else {
#pragma unroll
    for (int s = 0; s < 4; ++s)
      gload16(Wf + (size_t)cts[s] * 4096 + t * 8, &blds[(s * 512 + t) * 8]);
  }

  // ---- A half0 (kt 0-3) loads + convert, concurrent with B stage ----
  const float* arp = (isv ? zin : feat) + (size_t)arow * 256;
  float4 raw[8];
#pragma unroll
  for (int kt = 0; kt < 4; ++kt) {
    raw[kt * 2]     = *(const float4*)(arp + kt * 32 + g * 8);
    raw[kt * 2 + 1] = *(const float4*)(arp + kt * 32 + g * 8 + 4);
  }
  f16x8 Ah[4], Al[4];
  cvt_half(raw, Ah, Al);
  __syncthreads();            // B ready (drains gload queue)

  // ---- issue A half1 loads: in flight under half0 MFMAs ----
#pragma unroll
  for (int kt = 0; kt < 4; ++kt) {
    raw[kt * 2]     = *(const float4*)(arp + (kt + 4) * 32 + g * 8);
    raw[kt * 2 + 1] = *(const float4*)(arp + (kt + 4) * 32 + g * 8 + 4);
  }

  f32x4 acc[6];
#pragma unroll
  for (int s = 0; s < 6; ++s) acc[s] = (f32x4){0.f, 0.f, 0.f, 0.f};

  if (!isv) {
    mfma_half<6>(blds, 0, Ah, Al, lane, acc);
    cvt_half(raw, Ah, Al);
    mfma_half<6>(blds, 4, Ah, Al, lane, acc);
  } else {
    mfma_half<4>(blds, 0, Ah, Al, lane, acc);
    cvt_half(raw, Ah, Al);
    mfma_half<4>(blds, 4, Ah, Al, lane, acc);
  }

  // ---- epilogues (all wave-local) ----
  if (!isv) {
#pragma unroll
    for (int s = 0; s < 6; ++s) {
      const float bb = bbig[cts[s] * 16 + cl];
#pragma unroll
      for (int j = 0; j < 4; ++j) acc[s][j] += bb;
    }
    const float sc = rsqrtf(tau[0]) * SCALE_D4;
    const float h2 = 0.5f * sc * sc;
    float ds[4];
#pragma unroll
    for (int j = 0; j < 4; ++j)
      ds[j] = acc[0][j] * acc[0][j] + acc[1][j] * acc[1][j] +
              acc[2][j] * acc[2][j] + acc[3][j] * acc[3][j];
#pragma unroll
    for (int m = 1; m < 16; m <<= 1) {
#pragma unroll
      for (int j = 0; j < 4; ++j) ds[j] += __shfl_xor(ds[j], m);
    }
    float wmax = -3.4e38f;
#pragma unroll
    for (int j = 0; j < 4; ++j) {
      const float x0 = acc[4][j], x1 = acc[5][j];
      float mv = fmaxf(x0, (cl < 14) ? x1 : -3.4e38f);
#pragma unroll
      for (int m = 1; m < 16; m <<= 1) mv = fmaxf(mv, __shfl_xor(mv, m));
      const float dg = h2 * ds[j];
      const int r = rbase + 4 * g + j;
      if (qk == 0) {
        if (r < NN) {
          float* dst = qp + (size_t)r * 120 + h * 30;
          dst[cl] = RATIO_F * (expf(x0 - dg - mv) + EPS_F);
          if (cl < 14) dst[16 + cl] = RATIO_F * (expf(x1 - dg - mv) + EPS_F);
        }
      } else {
        wmax = fmaxf(wmax, mv);
        if (r < NN) {
          float* dst = kbuf + (size_t)r * 120 + h * 30;
          dst[cl] = x0 - dg;
          if (cl < 14) dst[16 + cl] = x1 - dg;
        }
      }
    }
    if (qk) {
      wmax = fmaxf(wmax, __shfl_xor(wmax, 16));
      wmax = fmaxf(wmax, __shfl_xor(wmax, 32));
      if (lane == 0) atomicMax(&kmaxU[h], fenc(wmax));
    }
  } else {
#pragma unroll
    for (int s = 0; s < 4; ++s) {
      const float bb = bbig[cts[s] * 16 + cl];
      const int colb = (cts[s] - 32) * 16 + cl;
#pragma unroll
      for (int j = 0; j < 4; ++j) {
        const int r = rbase + 4 * g + j;
        if (r < NN) vh[(size_t)r * 256 + colb] = (_Float16)(acc[s][j] + bb);
      }
    }
  }
}

// ------------- K3a: per-chunk partials of kvs/ksum (no atomics) -------------
__global__ __launch_bounds__(256)
void k3_kvs(const float* __restrict__ kbr, const _Float16* __restrict__ vh,
            const unsigned* __restrict__ kmaxU, float* __restrict__ partial) {
  __shared__ float kpch[128 * 32];
  __shared__ float vch[128 * 68];
  const int h = blockIdx.y;
  const int n0 = blockIdx.x * 128;
  const int cnt = min(128, NN - n0);
  const int t = threadIdx.x;
  const float mx = fdec(kmaxU[h]);
  const int m = t >> 3, dg = t & 7, d0 = dg * 8;
#pragma unroll
  for (int l = 0; l < 15; ++l) {
    const int flat = l * 256 + t;
    const int nl = flat / 30, mm = flat - nl * 30;
    kpch[nl * 32 + mm] = (nl < cnt)
        ? RATIO_F * (expf(kbr[(size_t)(n0 + nl) * 120 + h * 30 + mm] - mx) + EPS_F)
        : 0.f;
  }
#pragma unroll
  for (int l = 0; l < 8; ++l) {
    const int f4 = l * 256 + t;
    const int nl = f4 >> 4, dd = (f4 & 15) * 4;
    float4 vv = make_float4(0.f, 0.f, 0.f, 0.f);
    if (nl < cnt) {
      f16x4 u = *(const f16x4*)(vh + (size_t)(n0 + nl) * 256 + h * 64 + dd);
      vv = make_float4((float)u[0], (float)u[1], (float)u[2], (float)u[3]);
    }
    *(float4*)&vch[nl * 68 + dd] = vv;
  }
  __syncthreads();
  float acc[8] = {0, 0, 0, 0, 0, 0, 0, 0};
  float asum = 0.f;
  const int ms = (m < 30) ? m : 0;
  for (int nl = 0; nl < cnt; ++nl) {
    const float kv = kpch[nl * 32 + ms];
    const float4 va = *(const float4*)&vch[nl * 68 + d0];
    const float4 vb = *(const float4*)&vch[nl * 68 + d0 + 4];
    fma4(&acc[0], kv, va);
    fma4(&acc[4], kv, vb);
    asum += kv;
  }
  if (m < 30) {
    float* dst = partial + ((size_t)blockIdx.y * NCH + blockIdx.x) * 1952 + m * 64 + d0;
#pragma unroll
    for (int j = 0; j < 8; ++j) dst[j] = acc[j];
    if (dg == 0)
      partial[((size_t)blockIdx.y * NCH + blockIdx.x) * 1952 + 1920 + m] = asum;
  }
}

// ------------- K3b: reduce partials -> kvs, ksum -------------
__global__ __launch_bounds__(256)
void k3b_reduce(const float* __restrict__ partial, float* __restrict__ kvs,
                float* __restrict__ ksum) {
  const int idx = blockIdx.x * 256 + threadIdx.x;
  if (idx >= 4 * 1952) return;
  const int h = idx / 1952, q = idx - h * 1952;
  float s = 0.f;
  for (int c = 0; c < NCH; ++c)
    s += partial[((size_t)h * NCH + c) * 1952 + q];
  if (q < 1920) kvs[h * 1920 + q] = s;
  else if (q < 1950) ksum[h * 30 + (q - 1920)] = s;
}

// ------------- K4: num/den -> zbuf -------------
__global__ __launch_bounds__(256)
void k4_attn(const float* __restrict__ qp, const float* __restrict__ kvs,
             const float* __restrict__ ksum, float* __restrict__ zbuf) {
  __shared__ float kvsl[120 * 68];
  __shared__ float ksl[120];
  __shared__ float qpl[32 * 120];
  const int t = threadIdx.x;
  const int n0 = blockIdx.x * 32;
#pragma unroll
  for (int l = 0; l < 30; ++l) {
    const int f = l * 256 + t;           // 7680
    const int hm = f >> 6, d = f & 63;
    kvsl[hm * 68 + d] = kvs[f];
  }
  if (t < 120) ksl[t] = ksum[t];
#pragma unroll
  for (int l = 0; l < 15; ++l) {
    const int f = l * 256 + t;           // 3840
    qpl[f] = qp[(size_t)n0 * 120 + f];
  }
  __syncthreads();
  const int nl = t >> 3, dg = t & 7, d0 = dg * 8;
  const float* qrow = &qpl[nl * 120];
  float den[4] = {0, 0, 0, 0};
  for (int m = 0; m < 30; ++m) {
#pragma unroll
    for (int hh = 0; hh < 4; ++hh) den[hh] = fmaf(qrow[hh * 30 + m], ksl[hh * 30 + m], den[hh]);
  }
  float acc[4][8] = {};
  for (int m = 0; m < 30; ++m) {
#pragma unroll
    for (int hh = 0; hh < 4; ++hh) {
      const float qv = qrow[hh * 30 + m];
      const float* kr = &kvsl[(hh * 30 + m) * 68 + d0];
      const float4 ka = *(const float4*)kr;
      const float4 kb = *(const float4*)(kr + 4);
      fma4(&acc[hh][0], qv, ka);
      fma4(&acc[hh][4], qv, kb);
    }
  }
  const size_t n = n0 + nl;
#pragma unroll
  for (int hh = 0; hh < 4; ++hh) {
    const float inv = 1.0f / den[hh];
    float4 o1 = make_float4(acc[hh][0] * inv, acc[hh][1] * inv, acc[hh][2] * inv, acc[hh][3] * inv);
    float4 o2 = make_float4(acc[hh][4] * inv, acc[hh][5] * inv, acc[hh][6] * inv, acc[hh][7] * inv);
    *(float4*)(zbuf + n * 256 + hh * 64 + d0) = o1;
    *(float4*)(zbuf + n * 256 + hh * 64 + d0 + 4) = o2;
  }
}

// ------------- K5: degree counts (int4 vectorized) -------------
__global__ __launch_bounds__(256)
void k5_deg(const int* __restrict__ ei, int* __restrict__ dini, int* __restrict__ douti) {
  const int q = blockIdx.x * 256 + threadIdx.x;
  if (q >= EE / 4) return;
  const int4 r4 = *(const int4*)(ei + q * 4);
  const int4 c4 = *(const int4*)(ei + EE + q * 4);
  atomicAdd(&dini[c4.x], 1); atomicAdd(&dini[c4.y], 1);
  atomicAdd(&dini[c4.z], 1); atomicAdd(&dini[c4.w], 1);
  atomicAdd(&douti[r4.x], 1); atomicAdd(&douti[r4.y], 1);
  atomicAdd(&douti[r4.z], 1); atomicAdd(&douti[r4.w], 1);
}

// ------------- K6a: exclusive scan of in-degrees (1024 threads, int4) -------------
__global__ __launch_bounds__(1024)
void k6a_scan(const int* __restrict__ cnt, int* __restrict__ off) {
  __shared__ int s[1024];
  const int t = threadIdx.x;
  int4 v[5];
  int sum = 0;
  const int4* p4 = (const int4*)(cnt + t * 20);
#pragma unroll
  for (int i = 0; i < 5; ++i) {
    v[i] = p4[i];
    sum += v[i].x + v[i].y + v[i].z + v[i].w;
  }
  s[t] = sum;
  __syncthreads();
  for (int o = 1; o < 1024; o <<= 1) {
    const int add = (t >= o) ? s[t - o] : 0;
    __syncthreads();
    s[t] += add;
    __syncthreads();
  }
  int run = (t == 0) ? 0 : s[t - 1];
  if (t == 0) off[0] = 0;
  const int base = t * 20;
#pragma unroll
  for (int i = 0; i < 5; ++i) {
    const int vals[4] = {v[i].x, v[i].y, v[i].z, v[i].w};
#pragma unroll
    for (int j = 0; j < 4; ++j) {
      const int idx = base + i * 4 + j;
      if (idx < NN) { run += vals[j]; off[idx + 1] = run; }
    }
  }
}

// ------------- K6b: fill CSR (rows bucketed by col) -------------
__global__ __launch_bounds__(256)
void k6b_fill(const int* __restrict__ ei, const int* __restrict__ coff,
              int* __restrict__ cursor, int* __restrict__ crow) {
  const int e = blockIdx.x * 256 + threadIdx.x;
  const int r = ei[e], c = ei[EE + e];
  const int pos = atomicAdd(&cursor[c], 1);
  crow[coff[c] + pos] = r;
}

// ------------- K6c: rw[n] = rsqrt(out-degree) (shortens k7 dep chain) -----
__global__ __launch_bounds__(256)
void k6c_rw(const int* __restrict__ douti, float* __restrict__ rw) {
  const int n = blockIdx.x * 256 + threadIdx.x;
  if (n < NN) rw[n] = rsqrtf((float)douti[n]);
}

// ------------- K7: gather relational bias; one wave per node -------------
__global__ __launch_bounds__(256)
void k7_gather(const int* __restrict__ coff, const int* __restrict__ crow,
               const float* __restrict__ rw, const _Float16* __restrict__ vh,
               const float* __restrict__ bp, float* __restrict__ zbuf) {
  const int node = blockIdx.x * 4 + (threadIdx.x >> 6);
  const int lane = threadIdx.x & 63;
  const int o0 = coff[node], o1 = coff[node + 1];
  float a0 = 0.f, a1 = 0.f, a2 = 0.f, a3 = 0.f;
  if (o1 > o0) {
    int e = o0;
    for (; e + 8 <= o1; e += 8) {
      int rr[8];
#pragma unroll
      for (int u = 0; u < 8; ++u) rr[u] = crow[e + u];
      float ww[8];
#pragma unroll
      for (int u = 0; u < 8; ++u) ww[u] = rw[rr[u]];
#pragma unroll
      for (int u = 0; u < 8; ++u) {
        const f16x4 vv = *(const f16x4*)(vh + (size_t)rr[u] * 256 + lane * 4);
        a0 = fmaf(ww[u], (float)vv[0], a0);
        a1 = fmaf(ww[u], (float)vv[1], a1);
        a2 = fmaf(ww[u], (float)vv[2], a2);
        a3 = fmaf(ww[u], (float)vv[3], a3);
      }
    }
    for (; e < o1; ++e) {
      const int r = crow[e];
      const float wr = rw[r];
      const f16x4 vv = *(const f16x4*)(vh + (size_t)r * 256 + lane * 4);
      a0 = fmaf(wr, (float)vv[0], a0);
      a1 = fmaf(wr, (float)vv[1], a1);
      a2 = fmaf(wr, (float)vv[2], a2);
      a3 = fmaf(wr, (float)vv[3], a3);
    }
    const float rin = rsqrtf((float)(o1 - o0));
    a0 *= rin; a1 *= rin; a2 *= rin; a3 *= rin;
  }
  const float sg = 1.f / (1.f + expf(-bp[lane >> 4]));   // head = (lane*4)>>6
  float* dst = zbuf + (size_t)node * 256 + lane * 4;
  const float4 old = *(const float4*)dst;
  *(float4*)dst = make_float4(old.x + sg * a0, old.y + sg * a1,
                              old.z + sg * a2, old.w + sg * a3);
}

// ------------- K8: out = zbuf @ Wo^T + bo -------------
__global__ __launch_bounds__(256)
void k8_out(const float* __restrict__ zbuf, const float* __restrict__ Wo,
            const float* __restrict__ bo, float* __restrict__ out) {
  __shared__ float WoT[256 * 33];
  __shared__ float zbl[8 * 256];
  const int t = threadIdx.x;
  const int ch = blockIdx.y;  // 0/1 -> output cols [ch*32, ch*32+32)
#pragma unroll
  for (int l = 0; l < 32; ++l) {
    WoT[t * 33 + l] = Wo[(ch * 32 + l) * 256 + t];
  }
  const int nl = t >> 5, cp = t & 31;
  const float bias = bo[ch * 32 + cp];
  for (int g = blockIdx.x; g < 2500; g += gridDim.x) {
    __syncthreads();
#pragma unroll
    for (int l = 0; l < 2; ++l) {
      const int f4 = l * 256 + t;
      *(float4*)&zbl[f4 * 4] = *(const float4*)(zbuf + (size_t)g * 2048 + f4 * 4);
    }
    __syncthreads();
    float acc = bias;
#pragma unroll
    for (int i4 = 0; i4 < 64; ++i4) {
      const float4 z4 = *(const float4*)&zbl[nl * 256 + i4 * 4];
      acc = fmaf(z4.x, WoT[(i4 * 4 + 0) * 33 + cp], acc);
      acc = fmaf(z4.y, WoT[(i4 * 4 + 1) * 33 + cp], acc);
      acc = fmaf(z4.z, WoT[(i4 * 4 + 2) * 33 + cp], acc);
      acc = fmaf(z4.w, WoT[(i4 * 4 + 3) * 33 + cp], acc);
    }
    out[((size_t)g * 8 + nl) * 64 + ch * 32 + cp] = acc;
  }
}

extern "C" void kernel_launch(void* const* d_in, const int* in_sizes, int n_in,
                              void* d_out, int out_size, void* d_ws, size_t ws_size,
                              hipStream_t stream) {
  (void)in_sizes; (void)n_in; (void)out_size; (void)ws_size;
  const float* z    = (const float*)d_in[0];
  const float* feat = (const float*)d_in[1];
  const int*   ei   = (const int*)d_in[2];
  const float* tau  = (const float*)d_in[3];
  const float* Wq_w = (const float*)d_in[4];
  const float* Wq_b = (const float*)d_in[5];
  const float* Wk_w = (const float*)d_in[6];
  const float* Wk_b = (const float*)d_in[7];
  const float* Wv_w = (const float*)d_in[8];
  const float* Wv_b = (const float*)d_in[9];
  const float* Wo_w = (const float*)d_in[10];
  const float* Wo_b = (const float*)d_in[11];
  const float* bp   = (const float*)d_in[12];
  const float* proj = (const float*)d_in[13];
  float* out = (float*)d_out;

  char* p = (char*)d_ws;
  auto alloc = [&](size_t bytes) { char* r = p; p += (bytes + 255) & ~(size_t)255; return r; };
  _Float16* Wf    = (_Float16*)alloc((size_t)256 * 1024 * 2);
  float*    bbig  = (float*)alloc(1024 * 4);
  _Float16* vh    = (_Float16*)alloc((size_t)NN * 256 * 2);
  float*    qp    = (float*)alloc((size_t)NN * 120 * 4);
  float*    kbuf  = (float*)alloc((size_t)NN * 120 * 4);
  float*    zbuf  = (float*)alloc((size_t)NN * 256 * 4);
  float*    partial = (float*)alloc((size_t)4 * NCH * 1952 * 4);
  float*    kvs   = (float*)alloc(7680 * 4);
  float*    ksum  = (float*)alloc(120 * 4);
  float*    rw    = (float*)alloc((size_t)NN * 4);
  // ---- contiguous zero-region ----
  char* z0 = p;
  unsigned* kmaxU = (unsigned*)alloc(16);
  int*      dini  = (int*)alloc((size_t)20480 * 4);   // padded for int4 scan
  int*      douti = (int*)alloc((size_t)NN * 4);
  int*      cursor= (int*)alloc((size_t)NN * 4);
  char* z1 = p;
  int*      coff  = (int*)alloc((size_t)(NN + 1) * 4);
  int*      crow  = (int*)alloc((size_t)EE * 4);

  hipMemsetAsync(z0, 0, (size_t)(z1 - z0), stream);

  k0_build<<<1024, 256, 0, stream>>>(Wq_w, Wk_w, Wv_w, Wq_b, Wk_b, Wv_b, proj, tau, Wf, bbig);
  k5_deg<<<(EE / 4 + 255) / 256, 256, 0, stream>>>(ei, dini, douti);
  k6a_scan<<<1, 1024, 0, stream>>>(dini, coff);
  k6b_fill<<<EE / 256, 256, 0, stream>>>(ei, coff, cursor, crow);
  k6c_rw<<<(NN + 255) / 256, 256, 0, stream>>>(douti, rw);
  k1_all<<<dim3(157, 12), 512, 0, stream>>>(feat, z, Wf, bbig, tau, qp, kbuf, vh, kmaxU);
  k3_kvs<<<dim3(NCH, 4), 256, 0, stream>>>(kbuf, vh, kmaxU, partial);
  k3b_reduce<<<(4 * 1952 + 255) / 256, 256, 0, stream>>>(partial, kvs, ksum);
  k4_attn<<<NN / 32, 256, 0, stream>>>(qp, kvs, ksum, zbuf);
  k7_gather<<<NN / 4, 256, 0, stream>>>(coff, crow, rw, vh, bp, zbuf);
  k8_out<<<dim3(512, 2), 256, 0, stream>>>(zbuf, Wo_w, Wo_b, out);
}

// Round 9
// 325.278 us; speedup vs baseline: 1.0220x; 1.0220x over previous
//
#include <hip/hip_runtime.h>

#define NN 20000
#define EE 320000
#define RATIO_F 0.18257418583505536f   // 1/sqrt(30)
#define EPS_F 1e-6f
#define SCALE_D4 0.35355339059327373f  // 64^-0.25
#define NCH 157                        // ceil(20000/128) k3 chunks

typedef _Float16 f16x8 __attribute__((ext_vector_type(8)));
typedef _Float16 f16x4 __attribute__((ext_vector_type(4)));
typedef float f32x4 __attribute__((ext_vector_type(4)));

__device__ __forceinline__ unsigned fenc(float x) {
  unsigned u = __float_as_uint(x);
  return (u & 0x80000000u) ? ~u : (u | 0x80000000u);
}
__device__ __forceinline__ float fdec(unsigned u) {
  return (u & 0x80000000u) ? __uint_as_float(u & 0x7FFFFFFFu) : __uint_as_float(~u);
}
__device__ __forceinline__ void fma4(float* a, float s, float4 b) {
  a[0] = fmaf(s, b.x, a[0]);
  a[1] = fmaf(s, b.y, a[1]);
  a[2] = fmaf(s, b.z, a[2]);
  a[3] = fmaf(s, b.w, a[3]);
}
// async global->LDS, 16B per lane; LDS dest must be wave-uniform base + lane*16
__device__ __forceinline__ void gload16(const void* g, void* l) {
  __builtin_amdgcn_global_load_lds(
      (const __attribute__((address_space(1))) unsigned int*)g,
      (__attribute__((address_space(3))) unsigned int*)l, 16, 0, 0);
}

// =====================================================================
// K0: build fused weight plane (f16) in MFMA B-fragment order.
// Columns (1024 = 64 cts): [0,256)=q  [256,512)=k  [512,768)=v
//   xd_q head h = cts 48+2h,49+2h (m<30 valid); xd_k head h = cts 56+2h,57+2h
// Fragment fi = ct*8+kt (512 f16); lane l=(g*16+cl), elem j holds
// W[k=32*kt+8*g+j][col=ct*16+cl].
// =====================================================================
__global__ __launch_bounds__(256)
void k0_build(const float* __restrict__ Wq, const float* __restrict__ Wk,
              const float* __restrict__ Wv, const float* __restrict__ bq,
              const float* __restrict__ bk, const float* __restrict__ bv,
              const float* __restrict__ proj, const float* __restrict__ tau,
              _Float16* __restrict__ Wf, float* __restrict__ bbig) {
  const int col = blockIdx.x;
  const int i = threadIdx.x;   // k index
  const float s = rsqrtf(tau[0]) * SCALE_D4;
  float val = 0.f, bias = 0.f;
  if (col < 256) {
    val = Wq[col * 256 + i]; bias = bq[col];
  } else if (col < 512) {
    const int c = col - 256;
    val = Wk[c * 256 + i]; bias = bk[c];
  } else if (col < 768) {
    const int c = col - 512;
    val = Wv[c * 256 + i]; bias = bv[c];
  } else {
    const int rr = col - 768;
    const int grp = rr >> 7;             // 0 = q, 1 = k
    const int h = (rr >> 5) & 3, m = rr & 31;
    if (m < 30) {
      const float* W = grp ? Wk : Wq;
      const float* bb = grp ? bk : bq;
      float a = 0.f, ba = 0.f;
#pragma unroll 8
      for (int d = 0; d < 64; ++d) {
        const float pr = proj[m * 64 + d];
        a  = fmaf(pr, W[(h * 64 + d) * 256 + i], a);
        ba = fmaf(pr, bb[h * 64 + d], ba);
      }
      val = s * a; bias = s * ba;
    }
  }
  const int kt = i >> 5, gg = (i >> 3) & 3, j = i & 7;
  const int lane = gg * 16 + (col & 15);
  const size_t off = (size_t)((col >> 4) * 8 + kt) * 512 + lane * 8 + j;
  Wf[off] = (_Float16)val;
  if (i == 0) bbig[col] = bias;
}

// ---- K0b: Wo (64x256) -> hi/lo f16 fragment planes (4 cts) ----
__global__ __launch_bounds__(256)
void k0b_wo(const float* __restrict__ Wo, _Float16* __restrict__ WoFh,
            _Float16* __restrict__ WoFl) {
  const int col = blockIdx.x;      // 0..63 output col
  const int i = threadIdx.x;       // k index
  const float val = Wo[col * 256 + i];
  const int kt = i >> 5, gg = (i >> 3) & 3, j = i & 7;
  const int lane = gg * 16 + (col & 15);
  const size_t off = (size_t)((col >> 4) * 8 + kt) * 512 + lane * 8 + j;
  const _Float16 hb = (_Float16)val;
  WoFh[off] = hb;
  WoFl[off] = (_Float16)(val - (float)hb);
}

// ---- A-fragment loader: 16 rows x 256 K of f32 -> f16 hi + f16 residual ----
__device__ __forceinline__ void load_frags16(const float* __restrict__ p, int g,
                                             f16x8* Ah, f16x8* Al) {
#pragma unroll
  for (int hv = 0; hv < 2; ++hv) {
    float4 fr[8];
#pragma unroll
    for (int kt = 0; kt < 4; ++kt) {
      fr[kt * 2]     = *(const float4*)(p + (hv * 4 + kt) * 32 + g * 8);
      fr[kt * 2 + 1] = *(const float4*)(p + (hv * 4 + kt) * 32 + g * 8 + 4);
    }
#pragma unroll
    for (int kt = 0; kt < 4; ++kt) {
      const float ff[8] = {fr[kt*2].x, fr[kt*2].y, fr[kt*2].z, fr[kt*2].w,
                           fr[kt*2+1].x, fr[kt*2+1].y, fr[kt*2+1].z, fr[kt*2+1].w};
      union { _Float16 h[8]; f16x8 v; } hu, lu;
#pragma unroll
      for (int j = 0; j < 8; ++j) {
        const _Float16 hb = (_Float16)ff[j];
        hu.h[j] = hb;
        lu.h[j] = (_Float16)(ff[j] - (float)hb);
      }
      Ah[hv * 4 + kt] = hu.v; Al[hv * 4 + kt] = lu.v;
    }
  }
}

// ---- one 16x16 C-tile over K=256, B from LDS slot (conflict-free b128) ----
__device__ __forceinline__ f32x4 ct_lds(const _Float16* __restrict__ blds,
                                        int slot, int lane, float bb,
                                        const f16x8* Ah, const f16x8* Al) {
  const _Float16* bp = blds + slot * 4096 + lane * 8;
  f16x8 bfr[8];
#pragma unroll
  for (int kt = 0; kt < 8; ++kt)
    bfr[kt] = *(const f16x8*)(bp + kt * 512);
  f32x4 a0 = {0.f, 0.f, 0.f, 0.f}, a1 = {0.f, 0.f, 0.f, 0.f};
#pragma unroll
  for (int kt = 0; kt < 8; ++kt) {
    a0 = __builtin_amdgcn_mfma_f32_16x16x32_f16(Ah[kt], bfr[kt], a0, 0, 0, 0);
    a1 = __builtin_amdgcn_mfma_f32_16x16x32_f16(Al[kt], bfr[kt], a1, 0, 0, 0);
  }
  f32x4 r;
#pragma unroll
  for (int j = 0; j < 4; ++j) r[j] = a0[j] + a1[j] + bb;
  return r;
}

// =====================================================================
// K1 (R7-best): merged q/k/xd/v GEMM. grid (157, 6) x 512 thr.
//  y<4: head y. Stage q+k cts (64 KB) via global_load_lds -> diag ->
//       restage 4 xd cts -> softmax-kernel epilogues.
//  y=4,5: v col-half. Stage 8 cts -> store f16.
// =====================================================================
__global__ __launch_bounds__(512, 4)
void k1_all(const float* __restrict__ feat, const float* __restrict__ zin,
            const _Float16* __restrict__ Wf, const float* __restrict__ bbig,
            const float* __restrict__ tau,
            float* __restrict__ qp, float* __restrict__ kbuf,
            _Float16* __restrict__ vh, unsigned* __restrict__ kmaxU) {
  __shared__ __align__(16) _Float16 blds[8 * 4096];   // 64 KB
  const int t = threadIdx.x;
  const int wid = t >> 6, lane = t & 63;
  const int g = lane >> 4, cl = lane & 15;
  const int y = blockIdx.y;
  const int rbase = blockIdx.x * 128 + wid * 16;
  int arow = rbase + cl; if (arow > NN - 1) arow = NN - 1;

  f16x8 Ah[8], Al[8];

  if (y < 4) {
    const int h = y;
#pragma unroll
    for (int s = 0; s < 8; ++s) {
      const int ct = (s < 4) ? (h * 4 + s) : (16 + h * 4 + (s - 4));
      gload16(Wf + (size_t)ct * 4096 + t * 8, &blds[(s * 512 + t) * 8]);
    }
    load_frags16(feat + (size_t)arow * 256, g, Ah, Al);
    __syncthreads();

    const float sc = rsqrtf(tau[0]) * SCALE_D4;
    const float h2 = 0.5f * sc * sc;

    float dsq[4] = {0.f, 0.f, 0.f, 0.f}, dsk[4] = {0.f, 0.f, 0.f, 0.f};
#pragma unroll
    for (int c4 = 0; c4 < 4; ++c4) {
      const f32x4 a = ct_lds(blds, c4, lane, bbig[(h * 4 + c4) * 16 + cl], Ah, Al);
#pragma unroll
      for (int j = 0; j < 4; ++j) dsq[j] = fmaf(a[j], a[j], dsq[j]);
    }
#pragma unroll
    for (int c4 = 0; c4 < 4; ++c4) {
      const f32x4 a = ct_lds(blds, 4 + c4, lane, bbig[(16 + h * 4 + c4) * 16 + cl], Ah, Al);
#pragma unroll
      for (int j = 0; j < 4; ++j) dsk[j] = fmaf(a[j], a[j], dsk[j]);
    }
#pragma unroll
    for (int m = 1; m < 16; m <<= 1) {
#pragma unroll
      for (int j = 0; j < 4; ++j) {
        dsq[j] += __shfl_xor(dsq[j], m);
        dsk[j] += __shfl_xor(dsk[j], m);
      }
    }
    __syncthreads();
#pragma unroll
    for (int s = 0; s < 4; ++s) {
      const int ct = (s < 2) ? (48 + 2 * h + s) : (56 + 2 * h + (s - 2));
      gload16(Wf + (size_t)ct * 4096 + t * 8, &blds[(s * 512 + t) * 8]);
    }
    __syncthreads();

    {  // xd_q -> qp
      const f32x4 x0 = ct_lds(blds, 0, lane, bbig[(48 + 2 * h) * 16 + cl], Ah, Al);
      const f32x4 x1 = ct_lds(blds, 1, lane, bbig[(49 + 2 * h) * 16 + cl], Ah, Al);
#pragma unroll
      for (int j = 0; j < 4; ++j) {
        float mv = fmaxf(x0[j], (cl < 14) ? x1[j] : -3.4e38f);
#pragma unroll
        for (int m = 1; m < 16; m <<= 1) mv = fmaxf(mv, __shfl_xor(mv, m));
        const float dg = h2 * dsq[j];
        const int r = rbase + 4 * g + j;
        if (r < NN) {
          float* dst = qp + (size_t)r * 120 + h * 30;
          dst[cl] = RATIO_F * (expf(x0[j] - dg - mv) + EPS_F);
          if (cl < 14) dst[16 + cl] = RATIO_F * (expf(x1[j] - dg - mv) + EPS_F);
        }
      }
    }
    {  // xd_k -> kbuf + global head max
      const f32x4 x0 = ct_lds(blds, 2, lane, bbig[(56 + 2 * h) * 16 + cl], Ah, Al);
      const f32x4 x1 = ct_lds(blds, 3, lane, bbig[(57 + 2 * h) * 16 + cl], Ah, Al);
      float wmax = -3.4e38f;
#pragma unroll
      for (int j = 0; j < 4; ++j) {
        float mv = fmaxf(x0[j], (cl < 14) ? x1[j] : -3.4e38f);
#pragma unroll
        for (int m = 1; m < 16; m <<= 1) mv = fmaxf(mv, __shfl_xor(mv, m));
        wmax = fmaxf(wmax, mv);
        const float dg = h2 * dsk[j];
        const int r = rbase + 4 * g + j;
        if (r < NN) {
          float* dst = kbuf + (size_t)r * 120 + h * 30;
          dst[cl] = x0[j] - dg;
          if (cl < 14) dst[16 + cl] = x1[j] - dg;
        }
      }
      wmax = fmaxf(wmax, __shfl_xor(wmax, 16));
      wmax = fmaxf(wmax, __shfl_xor(wmax, 32));
      if (lane == 0) atomicMax(&kmaxU[h], fenc(wmax));
    }
  } else {
    const int ct0 = 32 + (y - 4) * 8;
#pragma unroll
    for (int s = 0; s < 8; ++s)
      gload16(Wf + (size_t)(ct0 + s) * 4096 + t * 8, &blds[(s * 512 + t) * 8]);
    load_frags16(zin + (size_t)arow * 256, g, Ah, Al);
    __syncthreads();
#pragma unroll
    for (int c = 0; c < 8; ++c) {
      const f32x4 a = ct_lds(blds, c, lane, bbig[(ct0 + c) * 16 + cl], Ah, Al);
      const int colb = (ct0 - 32 + c) * 16 + cl;
#pragma unroll
      for (int j = 0; j < 4; ++j) {
        const int r = rbase + 4 * g + j;
        if (r < NN) vh[(size_t)r * 256 + colb] = (_Float16)a[j];
      }
    }
  }
}

// ------------- K3a: per-chunk partials of kvs/ksum (no atomics) -------------
__global__ __launch_bounds__(256)
void k3_kvs(const float* __restrict__ kbr, const _Float16* __restrict__ vh,
            const unsigned* __restrict__ kmaxU, float* __restrict__ partial) {
  __shared__ float kpch[128 * 32];
  __shared__ float vch[128 * 68];
  const int h = blockIdx.y;
  const int n0 = blockIdx.x * 128;
  const int cnt = min(128, NN - n0);
  const int t = threadIdx.x;
  const float mx = fdec(kmaxU[h]);
  const int m = t >> 3, dg = t & 7, d0 = dg * 8;
#pragma unroll
  for (int l = 0; l < 15; ++l) {
    const int flat = l * 256 + t;
    const int nl = flat / 30, mm = flat - nl * 30;
    kpch[nl * 32 + mm] = (nl < cnt)
        ? RATIO_F * (expf(kbr[(size_t)(n0 + nl) * 120 + h * 30 + mm] - mx) + EPS_F)
        : 0.f;
  }
#pragma unroll
  for (int l = 0; l < 8; ++l) {
    const int f4 = l * 256 + t;
    const int nl = f4 >> 4, dd = (f4 & 15) * 4;
    float4 vv = make_float4(0.f, 0.f, 0.f, 0.f);
    if (nl < cnt) {
      f16x4 u = *(const f16x4*)(vh + (size_t)(n0 + nl) * 256 + h * 64 + dd);
      vv = make_float4((float)u[0], (float)u[1], (float)u[2], (float)u[3]);
    }
    *(float4*)&vch[nl * 68 + dd] = vv;
  }
  __syncthreads();
  float acc[8] = {0, 0, 0, 0, 0, 0, 0, 0};
  float asum = 0.f;
  const int ms = (m < 30) ? m : 0;
  for (int nl = 0; nl < cnt; ++nl) {
    const float kv = kpch[nl * 32 + ms];
    const float4 va = *(const float4*)&vch[nl * 68 + d0];
    const float4 vb = *(const float4*)&vch[nl * 68 + d0 + 4];
    fma4(&acc[0], kv, va);
    fma4(&acc[4], kv, vb);
    asum += kv;
  }
  if (m < 30) {
    float* dst = partial + ((size_t)blockIdx.y * NCH + blockIdx.x) * 1952 + m * 64 + d0;
#pragma unroll
    for (int j = 0; j < 8; ++j) dst[j] = acc[j];
    if (dg == 0)
      partial[((size_t)blockIdx.y * NCH + blockIdx.x) * 1952 + 1920 + m] = asum;
  }
}

// ------------- K3b: reduce partials -> kvs, ksum -------------
__global__ __launch_bounds__(256)
void k3b_reduce(const float* __restrict__ partial, float* __restrict__ kvs,
                float* __restrict__ ksum) {
  const int idx = blockIdx.x * 256 + threadIdx.x;
  if (idx >= 4 * 1952) return;
  const int h = idx / 1952, q = idx - h * 1952;
  float s = 0.f;
  for (int c = 0; c < NCH; ++c)
    s += partial[((size_t)h * NCH + c) * 1952 + q];
  if (q < 1920) kvs[h * 1920 + q] = s;
  else if (q < 1950) ksum[h * 30 + (q - 1920)] = s;
}

// =====================================================================
// K47: fused attention num/den + relational-bias gather -> zbuf (f32).
// 256 thr, 32 nodes/block. Phase A: k4 math -> zl LDS. Phase G: k7-style
// wave-per-node gather (lane owns 4 cols), adds into zl. Then one
// coalesced zbuf write. No zbuf RMW.
// =====================================================================
__global__ __launch_bounds__(256)
void k47_attn(const float* __restrict__ qp, const float* __restrict__ kvs,
              const float* __restrict__ ksum, const int* __restrict__ coff,
              const int* __restrict__ crow, const float* __restrict__ rw,
              const _Float16* __restrict__ vh, const float* __restrict__ bp,
              float* __restrict__ zbuf) {
  __shared__ float zl[32 * 260];
  __shared__ float kvsl[120 * 68];
  __shared__ float ksl[120];
  __shared__ float qpl[32 * 120];
  const int t = threadIdx.x;
  const int n0 = blockIdx.x * 32;
#pragma unroll
  for (int l = 0; l < 30; ++l) {
    const int f = l * 256 + t;           // 7680
    const int hm = f >> 6, d = f & 63;
    kvsl[hm * 68 + d] = kvs[f];
  }
  if (t < 120) ksl[t] = ksum[t];
#pragma unroll
  for (int l = 0; l < 15; ++l) {
    const int f = l * 256 + t;           // 3840
    qpl[f] = qp[(size_t)n0 * 120 + f];
  }
  __syncthreads();
  {
    const int nl = t >> 3, dg = t & 7, d0 = dg * 8;
    const float* qrow = &qpl[nl * 120];
    float den[4] = {0, 0, 0, 0};
    for (int m = 0; m < 30; ++m) {
#pragma unroll
      for (int hh = 0; hh < 4; ++hh)
        den[hh] = fmaf(qrow[hh * 30 + m], ksl[hh * 30 + m], den[hh]);
    }
    float acc[4][8] = {};
    for (int m = 0; m < 30; ++m) {
#pragma unroll
      for (int hh = 0; hh < 4; ++hh) {
        const float qv = qrow[hh * 30 + m];
        const float* kr = &kvsl[(hh * 30 + m) * 68 + d0];
        const float4 ka = *(const float4*)kr;
        const float4 kb = *(const float4*)(kr + 4);
        fma4(&acc[hh][0], qv, ka);
        fma4(&acc[hh][4], qv, kb);
      }
    }
#pragma unroll
    for (int hh = 0; hh < 4; ++hh) {
      const float inv = 1.0f / den[hh];
#pragma unroll
      for (int jj = 0; jj < 8; ++jj)
        zl[nl * 260 + hh * 64 + d0 + jj] = acc[hh][jj] * inv;
    }
  }
  __syncthreads();
  // ---- gather phase: wave wid handles nodes wid*8 .. wid*8+7 ----
  {
    const int wid = t >> 6, lane = t & 63;
    const float sg = 1.f / (1.f + expf(-bp[lane >> 4]));
    for (int u = 0; u < 8; ++u) {
      const int nodeL = wid * 8 + u;
      const int node = n0 + nodeL;
      const int o0 = coff[node], o1 = coff[node + 1];
      float a0 = 0.f, a1 = 0.f, a2 = 0.f, a3 = 0.f;
      if (o1 > o0) {
        int e = o0;
        for (; e + 8 <= o1; e += 8) {
          int rr[8];
#pragma unroll
          for (int q = 0; q < 8; ++q) rr[q] = crow[e + q];
          float ww[8];
#pragma unroll
          for (int q = 0; q < 8; ++q) ww[q] = rw[rr[q]];
#pragma unroll
          for (int q = 0; q < 8; ++q) {
            const f16x4 vv = *(const f16x4*)(vh + (size_t)rr[q] * 256 + lane * 4);
            a0 = fmaf(ww[q], (float)vv[0], a0);
            a1 = fmaf(ww[q], (float)vv[1], a1);
            a2 = fmaf(ww[q], (float)vv[2], a2);
            a3 = fmaf(ww[q], (float)vv[3], a3);
          }
        }
        for (; e < o1; ++e) {
          const int r = crow[e];
          const float wr = rw[r];
          const f16x4 vv = *(const f16x4*)(vh + (size_t)r * 256 + lane * 4);
          a0 = fmaf(wr, (float)vv[0], a0);
          a1 = fmaf(wr, (float)vv[1], a1);
          a2 = fmaf(wr, (float)vv[2], a2);
          a3 = fmaf(wr, (float)vv[3], a3);
        }
        const float rin = rsqrtf((float)(o1 - o0));
        float* zp = &zl[nodeL * 260 + lane * 4];
        zp[0] += sg * rin * a0;
        zp[1] += sg * rin * a1;
        zp[2] += sg * rin * a2;
        zp[3] += sg * rin * a3;
      }
    }
  }
  __syncthreads();
  // ---- coalesced zbuf write: 32 rows x 256 cols ----
#pragma unroll
  for (int l = 0; l < 8; ++l) {
    const int f4 = l * 256 + t;          // 2048 float4
    const int row = f4 >> 6, col4 = (f4 & 63) * 4;
    *(float4*)(zbuf + (size_t)(n0 + row) * 256 + col4) =
        *(const float4*)&zl[row * 260 + col4];
  }
}

// ------------- K5: degree counts (int4 vectorized) -------------
__global__ __launch_bounds__(256)
void k5_deg(const int* __restrict__ ei, int* __restrict__ dini, int* __restrict__ douti) {
  const int q = blockIdx.x * 256 + threadIdx.x;
  if (q >= EE / 4) return;
  const int4 r4 = *(const int4*)(ei + q * 4);
  const int4 c4 = *(const int4*)(ei + EE + q * 4);
  atomicAdd(&dini[c4.x], 1); atomicAdd(&dini[c4.y], 1);
  atomicAdd(&dini[c4.z], 1); atomicAdd(&dini[c4.w], 1);
  atomicAdd(&douti[r4.x], 1); atomicAdd(&douti[r4.y], 1);
  atomicAdd(&douti[r4.z], 1); atomicAdd(&douti[r4.w], 1);
}

// ------------- K6a: exclusive scan of in-degrees (1024 threads, int4) -------------
__global__ __launch_bounds__(1024)
void k6a_scan(const int* __restrict__ cnt, int* __restrict__ off) {
  __shared__ int s[1024];
  const int t = threadIdx.x;
  int4 v[5];
  int sum = 0;
  const int4* p4 = (const int4*)(cnt + t * 20);
#pragma unroll
  for (int i = 0; i < 5; ++i) {
    v[i] = p4[i];
    sum += v[i].x + v[i].y + v[i].z + v[i].w;
  }
  s[t] = sum;
  __syncthreads();
  for (int o = 1; o < 1024; o <<= 1) {
    const int add = (t >= o) ? s[t - o] : 0;
    __syncthreads();
    s[t] += add;
    __syncthreads();
  }
  int run = (t == 0) ? 0 : s[t - 1];
  if (t == 0) off[0] = 0;
  const int base = t * 20;
#pragma unroll
  for (int i = 0; i < 5; ++i) {
    const int vals[4] = {v[i].x, v[i].y, v[i].z, v[i].w};
#pragma unroll
    for (int j = 0; j < 4; ++j) {
      const int idx = base + i * 4 + j;
      if (idx < NN) { run += vals[j]; off[idx + 1] = run; }
    }
  }
}

// ------------- K6b: fill CSR (rows bucketed by col) -------------
__global__ __launch_bounds__(256)
void k6b_fill(const int* __restrict__ ei, const int* __restrict__ coff,
              int* __restrict__ cursor, int* __restrict__ crow) {
  const int e = blockIdx.x * 256 + threadIdx.x;
  const int r = ei[e], c = ei[EE + e];
  const int pos = atomicAdd(&cursor[c], 1);
  crow[coff[c] + pos] = r;
}

// ------------- K6c: rw[n] = rsqrt(out-degree) -------------
__global__ __launch_bounds__(256)
void k6c_rw(const int* __restrict__ douti, float* __restrict__ rw) {
  const int n = blockIdx.x * 256 + threadIdx.x;
  if (n < NN) rw[n] = rsqrtf((float)douti[n]);
}

// =====================================================================
// K8m: out = zbuf @ Wo^T + bo via MFMA (3-term f16 split).
// 157 blocks x 8 waves x 16 rows; WoF hi/lo (4 cts each, 64 KB) staged.
// =====================================================================
__global__ __launch_bounds__(512, 4)
void k8m_out(const float* __restrict__ zbuf, const _Float16* __restrict__ WoFh,
             const _Float16* __restrict__ WoFl, const float* __restrict__ bo,
             float* __restrict__ out) {
  __shared__ __align__(16) _Float16 blds[8 * 4096];   // 64 KB: 0-3 hi, 4-7 lo
  const int t = threadIdx.x;
  const int wid = t >> 6, lane = t & 63;
  const int g = lane >> 4, cl = lane & 15;
  const int rbase = blockIdx.x * 128 + wid * 16;
  int arow = rbase + cl; if (arow > NN - 1) arow = NN - 1;
#pragma unroll
  for (int s = 0; s < 4; ++s) {
    gload16(WoFh + (size_t)s * 4096 + t * 8, &blds[(s * 512 + t) * 8]);
    gload16(WoFl + (size_t)s * 4096 + t * 8, &blds[((s + 4) * 512 + t) * 8]);
  }
  f16x8 Ah[8], Al[8];
  load_frags16(zbuf + (size_t)arow * 256, g, Ah, Al);
  __syncthreads();
  f32x4 acc[4];
#pragma unroll
  for (int s = 0; s < 4; ++s) acc[s] = (f32x4){0.f, 0.f, 0.f, 0.f};
#pragma unroll
  for (int kt = 0; kt < 8; ++kt) {
#pragma unroll
    for (int s = 0; s < 4; ++s) {
      const f16x8 bh = *(const f16x8*)&blds[s * 4096 + kt * 512 + lane * 8];
      const f16x8 bl = *(const f16x8*)&blds[(s + 4) * 4096 + kt * 512 + lane * 8];
      acc[s] = __builtin_amdgcn_mfma_f32_16x16x32_f16(Ah[kt], bh, acc[s], 0, 0, 0);
      acc[s] = __builtin_amdgcn_mfma_f32_16x16x32_f16(Ah[kt], bl, acc[s], 0, 0, 0);
      acc[s] = __builtin_amdgcn_mfma_f32_16x16x32_f16(Al[kt], bh, acc[s], 0, 0, 0);
    }
  }
#pragma unroll
  for (int s = 0; s < 4; ++s) {
    const float bb = bo[s * 16 + cl];
#pragma unroll
    for (int j = 0; j < 4; ++j) {
      const int r = rbase + 4 * g + j;
      if (r < NN) out[(size_t)r * 64 + s * 16 + cl] = acc[s][j] + bb;
    }
  }
}

extern "C" void kernel_launch(void* const* d_in, const int* in_sizes, int n_in,
                              void* d_out, int out_size, void* d_ws, size_t ws_size,
                              hipStream_t stream) {
  (void)in_sizes; (void)n_in; (void)out_size; (void)ws_size;
  const float* z    = (const float*)d_in[0];
  const float* feat = (const float*)d_in[1];
  const int*   ei   = (const int*)d_in[2];
  const float* tau  = (const float*)d_in[3];
  const float* Wq_w = (const float*)d_in[4];
  const float* Wq_b = (const float*)d_in[5];
  const float* Wk_w = (const float*)d_in[6];
  const float* Wk_b = (const float*)d_in[7];
  const float* Wv_w = (const float*)d_in[8];
  const float* Wv_b = (const float*)d_in[9];
  const float* Wo_w = (const float*)d_in[10];
  const float* Wo_b = (const float*)d_in[11];
  const float* bp   = (const float*)d_in[12];
  const float* proj = (const float*)d_in[13];
  float* out = (float*)d_out;

  char* p = (char*)d_ws;
  auto alloc = [&](size_t bytes) { char* r = p; p += (bytes + 255) & ~(size_t)255; return r; };
  _Float16* Wf    = (_Float16*)alloc((size_t)256 * 1024 * 2);
  _Float16* WoFh  = (_Float16*)alloc((size_t)64 * 256 * 2);
  _Float16* WoFl  = (_Float16*)alloc((size_t)64 * 256 * 2);
  float*    bbig  = (float*)alloc(1024 * 4);
  _Float16* vh    = (_Float16*)alloc((size_t)NN * 256 * 2);
  float*    qp    = (float*)alloc((size_t)NN * 120 * 4);
  float*    kbuf  = (float*)alloc((size_t)NN * 120 * 4);
  float*    zbuf  = (float*)alloc((size_t)NN * 256 * 4);
  float*    partial = (float*)alloc((size_t)4 * NCH * 1952 * 4);
  float*    kvs   = (float*)alloc(7680 * 4);
  float*    ksum  = (float*)alloc(120 * 4);
  float*    rw    = (float*)alloc((size_t)NN * 4);
  // ---- contiguous zero-region ----
  char* z0 = p;
  unsigned* kmaxU = (unsigned*)alloc(16);
  int*      dini  = (int*)alloc((size_t)20480 * 4);   // padded for int4 scan
  int*      douti = (int*)alloc((size_t)NN * 4);
  int*      cursor= (int*)alloc((size_t)NN * 4);
  char* z1 = p;
  int*      coff  = (int*)alloc((size_t)(NN + 1) * 4);
  int*      crow  = (int*)alloc((size_t)EE * 4);

  hipMemsetAsync(z0, 0, (size_t)(z1 - z0), stream);

  k0_build<<<1024, 256, 0, stream>>>(Wq_w, Wk_w, Wv_w, Wq_b, Wk_b, Wv_b, proj, tau, Wf, bbig);
  k0b_wo<<<64, 256, 0, stream>>>(Wo_w, WoFh, WoFl);
  k5_deg<<<(EE / 4 + 255) / 256, 256, 0, stream>>>(ei, dini, douti);
  k6a_scan<<<1, 1024, 0, stream>>>(dini, coff);
  k6b_fill<<<EE / 256, 256, 0, stream>>>(ei, coff, cursor, crow);
  k6c_rw<<<(NN + 255) / 256, 256, 0, stream>>>(douti, rw);
  k1_all<<<dim3(157, 6), 512, 0, stream>>>(feat, z, Wf, bbig, tau, qp, kbuf, vh, kmaxU);
  k3_kvs<<<dim3(NCH, 4), 256, 0, stream>>>(kbuf, vh, kmaxU, partial);
  k3b_reduce<<<(4 * 1952 + 255) / 256, 256, 0, stream>>>(partial, kvs, ksum);
  k47_attn<<<NN / 32, 256, 0, stream>>>(qp, kvs, ksum, coff, crow, rw, vh, bp, zbuf);
  k8m_out<<<157, 512, 0, stream>>>(zbuf, WoFh, WoFl, Wo_b, out);
}

// Round 10
// 280.530 us; speedup vs baseline: 1.1850x; 1.1595x over previous
//
#include <hip/hip_runtime.h>

#define NN 20000
#define EE 320000
#define RATIO_F 0.18257418583505536f   // 1/sqrt(30)
#define EPS_F 1e-6f
#define SCALE_D4 0.35355339059327373f  // 64^-0.25
#define NCH 157                        // ceil(20000/128) k3 chunks

typedef _Float16 f16x8 __attribute__((ext_vector_type(8)));
typedef _Float16 f16x4 __attribute__((ext_vector_type(4)));
typedef float f32x4 __attribute__((ext_vector_type(4)));

__device__ __forceinline__ unsigned fenc(float x) {
  unsigned u = __float_as_uint(x);
  return (u & 0x80000000u) ? ~u : (u | 0x80000000u);
}
__device__ __forceinline__ float fdec(unsigned u) {
  return (u & 0x80000000u) ? __uint_as_float(u & 0x7FFFFFFFu) : __uint_as_float(~u);
}
__device__ __forceinline__ void fma4(float* a, float s, float4 b) {
  a[0] = fmaf(s, b.x, a[0]);
  a[1] = fmaf(s, b.y, a[1]);
  a[2] = fmaf(s, b.z, a[2]);
  a[3] = fmaf(s, b.w, a[3]);
}
// async global->LDS, 16B per lane; LDS dest must be wave-uniform base + lane*16
__device__ __forceinline__ void gload16(const void* g, void* l) {
  __builtin_amdgcn_global_load_lds(
      (const __attribute__((address_space(1))) unsigned int*)g,
      (__attribute__((address_space(3))) unsigned int*)l, 16, 0, 0);
}

// =====================================================================
// K0: build fused weight plane (f16) in MFMA B-fragment order.
// Columns (1024 = 64 cts): [0,256)=q  [256,512)=k  [512,768)=v
//   xd_q head h = cts 48+2h,49+2h (m<30 valid); xd_k head h = cts 56+2h,57+2h
// Fragment fi = ct*8+kt (512 f16); lane l=(g*16+cl), elem j holds
// W[k=32*kt+8*g+j][col=ct*16+cl].
// =====================================================================
__global__ __launch_bounds__(256)
void k0_build(const float* __restrict__ Wq, const float* __restrict__ Wk,
              const float* __restrict__ Wv, const float* __restrict__ bq,
              const float* __restrict__ bk, const float* __restrict__ bv,
              const float* __restrict__ proj, const float* __restrict__ tau,
              _Float16* __restrict__ Wf, float* __restrict__ bbig) {
  const int col = blockIdx.x;
  const int i = threadIdx.x;   // k index
  const float s = rsqrtf(tau[0]) * SCALE_D4;
  float val = 0.f, bias = 0.f;
  if (col < 256) {
    val = Wq[col * 256 + i]; bias = bq[col];
  } else if (col < 512) {
    const int c = col - 256;
    val = Wk[c * 256 + i]; bias = bk[c];
  } else if (col < 768) {
    const int c = col - 512;
    val = Wv[c * 256 + i]; bias = bv[c];
  } else {
    const int rr = col - 768;
    const int grp = rr >> 7;             // 0 = q, 1 = k
    const int h = (rr >> 5) & 3, m = rr & 31;
    if (m < 30) {
      const float* W = grp ? Wk : Wq;
      const float* bb = grp ? bk : bq;
      float a = 0.f, ba = 0.f;
#pragma unroll 8
      for (int d = 0; d < 64; ++d) {
        const float pr = proj[m * 64 + d];
        a  = fmaf(pr, W[(h * 64 + d) * 256 + i], a);
        ba = fmaf(pr, bb[h * 64 + d], ba);
      }
      val = s * a; bias = s * ba;
    }
  }
  const int kt = i >> 5, gg = (i >> 3) & 3, j = i & 7;
  const int lane = gg * 16 + (col & 15);
  const size_t off = (size_t)((col >> 4) * 8 + kt) * 512 + lane * 8 + j;
  Wf[off] = (_Float16)val;
  if (i == 0) bbig[col] = bias;
}

// ---- K0b: Wo (64x256) -> hi/lo f16 fragment planes (4 cts) ----
__global__ __launch_bounds__(256)
void k0b_wo(const float* __restrict__ Wo, _Float16* __restrict__ WoFh,
            _Float16* __restrict__ WoFl) {
  const int col = blockIdx.x;      // 0..63 output col
  const int i = threadIdx.x;       // k index
  const float val = Wo[col * 256 + i];
  const int kt = i >> 5, gg = (i >> 3) & 3, j = i & 7;
  const int lane = gg * 16 + (col & 15);
  const size_t off = (size_t)((col >> 4) * 8 + kt) * 512 + lane * 8 + j;
  const _Float16 hb = (_Float16)val;
  WoFh[off] = hb;
  WoFl[off] = (_Float16)(val - (float)hb);
}

// ---- convert 4 kt worth of raw float4 pairs -> f16 hi + f16 residual ----
__device__ __forceinline__ void cvt_half(const float4* raw, f16x8* Ah, f16x8* Al) {
#pragma unroll
  for (int kt = 0; kt < 4; ++kt) {
    const float ff[8] = {raw[kt*2].x, raw[kt*2].y, raw[kt*2].z, raw[kt*2].w,
                         raw[kt*2+1].x, raw[kt*2+1].y, raw[kt*2+1].z, raw[kt*2+1].w};
    union { _Float16 h[8]; f16x8 v; } hu, lu;
#pragma unroll
    for (int j = 0; j < 8; ++j) {
      const _Float16 hb = (_Float16)ff[j];
      hu.h[j] = hb;
      lu.h[j] = (_Float16)(ff[j] - (float)hb);
    }
    Ah[kt] = hu.v; Al[kt] = lu.v;
  }
}

// ---- ct index for slice slot s ----
__device__ __forceinline__ int ct_of(int s, int isv, int h, int y) {
  if (isv) return 32 + (y - 4) * 8 + s;
  if (s < 4)  return h * 4 + s;
  if (s < 8)  return 16 + h * 4 + (s - 4);
  if (s < 10) return 48 + 2 * h + (s - 8);
  return 56 + 2 * h + (s - 10);
}

// =====================================================================
// K1: grid (157, 6) x 512 thr (8 waves x 16 rows). K-split pipeline.
//  y<4: head y, 12 cts {q x4, k x4, xd_q x2, xd_k x2}. LDS holds one
//       K-half (kt0-3) of all 12 cts = 48 KB; two MFMA passes.
//  y=4,5: v col-half, 8 cts (32 KB of the 48).
// Flow: stage B-half0 + A-half0 loads + cvt -> barrier ->
//       issue A-half1 loads -> MFMA half0 (96) -> barrier ->
//       stage B-half1 -> cvt A-half1 -> barrier -> MFMA half1 -> epilogue.
// All reductions wave-local; 12 independent MFMA chains.
// =====================================================================
__global__ __launch_bounds__(512, 4)
void k1_all(const float* __restrict__ feat, const float* __restrict__ zin,
            const _Float16* __restrict__ Wf, const float* __restrict__ bbig,
            const float* __restrict__ tau,
            float* __restrict__ qp, float* __restrict__ kbuf,
            _Float16* __restrict__ vh, unsigned* __restrict__ kmaxU) {
  __shared__ __align__(16) _Float16 blds[12 * 2048];   // 48 KB
  const int t = threadIdx.x;
  const int wid = t >> 6, lane = t & 63;
  const int g = lane >> 4, cl = lane & 15;
  const int y = blockIdx.y;
  const int h = y & 3;
  const int rbase = blockIdx.x * 128 + wid * 16;
  int arow = rbase + cl; if (arow > NN - 1) arow = NN - 1;

  if (y < 4) {
    const float* arp = feat + (size_t)arow * 256;
    // ---- stage B half0: kt0-3 of 12 cts (48 KB) ----
#pragma unroll
    for (int r = 0; r < 6; ++r) {
      const int idx = r * 4096 + t * 8;
      const int s = idx >> 11, wi = idx & 2047;
      gload16(Wf + (size_t)ct_of(s, 0, h, y) * 4096 + wi, &blds[idx]);
    }
    float4 raw[8];
#pragma unroll
    for (int l = 0; l < 4; ++l) {
      raw[l * 2]     = *(const float4*)(arp + l * 32 + g * 8);
      raw[l * 2 + 1] = *(const float4*)(arp + l * 32 + g * 8 + 4);
    }
    f16x8 Ah[4], Al[4];
    cvt_half(raw, Ah, Al);
    __syncthreads();
    // ---- issue A half1 loads (fly under half0 MFMAs) ----
#pragma unroll
    for (int l = 0; l < 4; ++l) {
      raw[l * 2]     = *(const float4*)(arp + (l + 4) * 32 + g * 8);
      raw[l * 2 + 1] = *(const float4*)(arp + (l + 4) * 32 + g * 8 + 4);
    }
    f32x4 acc[12];
#pragma unroll
    for (int s = 0; s < 12; ++s) acc[s] = (f32x4){0.f, 0.f, 0.f, 0.f};
#pragma unroll
    for (int ktl = 0; ktl < 4; ++ktl) {
#pragma unroll
      for (int s = 0; s < 12; ++s) {
        const f16x8 b = *(const f16x8*)&blds[s * 2048 + ktl * 512 + lane * 8];
        acc[s] = __builtin_amdgcn_mfma_f32_16x16x32_f16(Ah[ktl], b, acc[s], 0, 0, 0);
        acc[s] = __builtin_amdgcn_mfma_f32_16x16x32_f16(Al[ktl], b, acc[s], 0, 0, 0);
      }
    }
    __syncthreads();   // everyone done reading half0
    // ---- stage B half1: kt4-7 ----
#pragma unroll
    for (int r = 0; r < 6; ++r) {
      const int idx = r * 4096 + t * 8;
      const int s = idx >> 11, wi = idx & 2047;
      gload16(Wf + (size_t)ct_of(s, 0, h, y) * 4096 + 2048 + wi, &blds[idx]);
    }
    cvt_half(raw, Ah, Al);
    __syncthreads();   // half1 staged
#pragma unroll
    for (int ktl = 0; ktl < 4; ++ktl) {
#pragma unroll
      for (int s = 0; s < 12; ++s) {
        const f16x8 b = *(const f16x8*)&blds[s * 2048 + ktl * 512 + lane * 8];
        acc[s] = __builtin_amdgcn_mfma_f32_16x16x32_f16(Ah[ktl], b, acc[s], 0, 0, 0);
        acc[s] = __builtin_amdgcn_mfma_f32_16x16x32_f16(Al[ktl], b, acc[s], 0, 0, 0);
      }
    }
    // ---- epilogue (wave-local) ----
#pragma unroll
    for (int s = 0; s < 12; ++s) {
      const float bb = bbig[ct_of(s, 0, h, y) * 16 + cl];
#pragma unroll
      for (int j = 0; j < 4; ++j) acc[s][j] += bb;
    }
    const float sc = rsqrtf(tau[0]) * SCALE_D4;
    const float h2 = 0.5f * sc * sc;
    float dsq[4], dsk[4];
#pragma unroll
    for (int j = 0; j < 4; ++j) {
      dsq[j] = acc[0][j] * acc[0][j] + acc[1][j] * acc[1][j] +
               acc[2][j] * acc[2][j] + acc[3][j] * acc[3][j];
      dsk[j] = acc[4][j] * acc[4][j] + acc[5][j] * acc[5][j] +
               acc[6][j] * acc[6][j] + acc[7][j] * acc[7][j];
    }
#pragma unroll
    for (int m = 1; m < 16; m <<= 1) {
#pragma unroll
      for (int j = 0; j < 4; ++j) {
        dsq[j] += __shfl_xor(dsq[j], m);
        dsk[j] += __shfl_xor(dsk[j], m);
      }
    }
    {  // xd_q -> qp
#pragma unroll
      for (int j = 0; j < 4; ++j) {
        const float x0 = acc[8][j], x1 = acc[9][j];
        float mv = fmaxf(x0, (cl < 14) ? x1 : -3.4e38f);
#pragma unroll
        for (int m = 1; m < 16; m <<= 1) mv = fmaxf(mv, __shfl_xor(mv, m));
        const float dg = h2 * dsq[j];
        const int r = rbase + 4 * g + j;
        if (r < NN) {
          float* dst = qp + (size_t)r * 120 + h * 30;
          dst[cl] = RATIO_F * (expf(x0 - dg - mv) + EPS_F);
          if (cl < 14) dst[16 + cl] = RATIO_F * (expf(x1 - dg - mv) + EPS_F);
        }
      }
    }
    {  // xd_k -> kbuf + global head max
      float wmax = -3.4e38f;
#pragma unroll
      for (int j = 0; j < 4; ++j) {
        const float x0 = acc[10][j], x1 = acc[11][j];
        float mv = fmaxf(x0, (cl < 14) ? x1 : -3.4e38f);
#pragma unroll
        for (int m = 1; m < 16; m <<= 1) mv = fmaxf(mv, __shfl_xor(mv, m));
        wmax = fmaxf(wmax, mv);
        const float dg = h2 * dsk[j];
        const int r = rbase + 4 * g + j;
        if (r < NN) {
          float* dst = kbuf + (size_t)r * 120 + h * 30;
          dst[cl] = x0 - dg;
          if (cl < 14) dst[16 + cl] = x1 - dg;
        }
      }
      wmax = fmaxf(wmax, __shfl_xor(wmax, 16));
      wmax = fmaxf(wmax, __shfl_xor(wmax, 32));
      if (lane == 0) atomicMax(&kmaxU[h], fenc(wmax));
    }
  } else {
    // ---- v col-half: 8 cts, K-split same pipeline ----
    const float* arp = zin + (size_t)arow * 256;
#pragma unroll
    for (int r = 0; r < 4; ++r) {
      const int idx = r * 4096 + t * 8;
      const int s = idx >> 11, wi = idx & 2047;
      gload16(Wf + (size_t)ct_of(s, 1, h, y) * 4096 + wi, &blds[idx]);
    }
    float4 raw[8];
#pragma unroll
    for (int l = 0; l < 4; ++l) {
      raw[l * 2]     = *(const float4*)(arp + l * 32 + g * 8);
      raw[l * 2 + 1] = *(const float4*)(arp + l * 32 + g * 8 + 4);
    }
    f16x8 Ah[4], Al[4];
    cvt_half(raw, Ah, Al);
    __syncthreads();
#pragma unroll
    for (int l = 0; l < 4; ++l) {
      raw[l * 2]     = *(const float4*)(arp + (l + 4) * 32 + g * 8);
      raw[l * 2 + 1] = *(const float4*)(arp + (l + 4) * 32 + g * 8 + 4);
    }
    f32x4 acc[8];
#pragma unroll
    for (int s = 0; s < 8; ++s) acc[s] = (f32x4){0.f, 0.f, 0.f, 0.f};
#pragma unroll
    for (int ktl = 0; ktl < 4; ++ktl) {
#pragma unroll
      for (int s = 0; s < 8; ++s) {
        const f16x8 b = *(const f16x8*)&blds[s * 2048 + ktl * 512 + lane * 8];
        acc[s] = __builtin_amdgcn_mfma_f32_16x16x32_f16(Ah[ktl], b, acc[s], 0, 0, 0);
        acc[s] = __builtin_amdgcn_mfma_f32_16x16x32_f16(Al[ktl], b, acc[s], 0, 0, 0);
      }
    }
    __syncthreads();
#pragma unroll
    for (int r = 0; r < 4; ++r) {
      const int idx = r * 4096 + t * 8;
      const int s = idx >> 11, wi = idx & 2047;
      gload16(Wf + (size_t)ct_of(s, 1, h, y) * 4096 + 2048 + wi, &blds[idx]);
    }
    cvt_half(raw, Ah, Al);
    __syncthreads();
#pragma unroll
    for (int ktl = 0; ktl < 4; ++ktl) {
#pragma unroll
      for (int s = 0; s < 8; ++s) {
        const f16x8 b = *(const f16x8*)&blds[s * 2048 + ktl * 512 + lane * 8];
        acc[s] = __builtin_amdgcn_mfma_f32_16x16x32_f16(Ah[ktl], b, acc[s], 0, 0, 0);
        acc[s] = __builtin_amdgcn_mfma_f32_16x16x32_f16(Al[ktl], b, acc[s], 0, 0, 0);
      }
    }
#pragma unroll
    for (int s = 0; s < 8; ++s) {
      const int ct = ct_of(s, 1, h, y);
      const float bb = bbig[ct * 16 + cl];
      const int colb = (ct - 32) * 16 + cl;
#pragma unroll
      for (int j = 0; j < 4; ++j) {
        const int r = rbase + 4 * g + j;
        if (r < NN) vh[(size_t)r * 256 + colb] = (_Float16)(acc[s][j] + bb);
      }
    }
  }
}

// ------------- K3a: per-chunk partials of kvs/ksum (no atomics) -------------
__global__ __launch_bounds__(256)
void k3_kvs(const float* __restrict__ kbr, const _Float16* __restrict__ vh,
            const unsigned* __restrict__ kmaxU, float* __restrict__ partial) {
  __shared__ float kpch[128 * 32];
  __shared__ float vch[128 * 68];
  const int h = blockIdx.y;
  const int n0 = blockIdx.x * 128;
  const int cnt = min(128, NN - n0);
  const int t = threadIdx.x;
  const float mx = fdec(kmaxU[h]);
  const int m = t >> 3, dg = t & 7, d0 = dg * 8;
#pragma unroll
  for (int l = 0; l < 15; ++l) {
    const int flat = l * 256 + t;
    const int nl = flat / 30, mm = flat - nl * 30;
    kpch[nl * 32 + mm] = (nl < cnt)
        ? RATIO_F * (expf(kbr[(size_t)(n0 + nl) * 120 + h * 30 + mm] - mx) + EPS_F)
        : 0.f;
  }
#pragma unroll
  for (int l = 0; l < 8; ++l) {
    const int f4 = l * 256 + t;
    const int nl = f4 >> 4, dd = (f4 & 15) * 4;
    float4 vv = make_float4(0.f, 0.f, 0.f, 0.f);
    if (nl < cnt) {
      f16x4 u = *(const f16x4*)(vh + (size_t)(n0 + nl) * 256 + h * 64 + dd);
      vv = make_float4((float)u[0], (float)u[1], (float)u[2], (float)u[3]);
    }
    *(float4*)&vch[nl * 68 + dd] = vv;
  }
  __syncthreads();
  float acc[8] = {0, 0, 0, 0, 0, 0, 0, 0};
  float asum = 0.f;
  const int ms = (m < 30) ? m : 0;
  for (int nl = 0; nl < cnt; ++nl) {
    const float kv = kpch[nl * 32 + ms];
    const float4 va = *(const float4*)&vch[nl * 68 + d0];
    const float4 vb = *(const float4*)&vch[nl * 68 + d0 + 4];
    fma4(&acc[0], kv, va);
    fma4(&acc[4], kv, vb);
    asum += kv;
  }
  if (m < 30) {
    float* dst = partial + ((size_t)blockIdx.y * NCH + blockIdx.x) * 1952 + m * 64 + d0;
#pragma unroll
    for (int j = 0; j < 8; ++j) dst[j] = acc[j];
    if (dg == 0)
      partial[((size_t)blockIdx.y * NCH + blockIdx.x) * 1952 + 1920 + m] = asum;
  }
}

// ------------- K3b: reduce partials -> kvs, ksum -------------
__global__ __launch_bounds__(256)
void k3b_reduce(const float* __restrict__ partial, float* __restrict__ kvs,
                float* __restrict__ ksum) {
  const int idx = blockIdx.x * 256 + threadIdx.x;
  if (idx >= 4 * 1952) return;
  const int h = idx / 1952, q = idx - h * 1952;
  float s = 0.f;
  for (int c = 0; c < NCH; ++c)
    s += partial[((size_t)h * NCH + c) * 1952 + q];
  if (q < 1920) kvs[h * 1920 + q] = s;
  else if (q < 1950) ksum[h * 30 + (q - 1920)] = s;
}

// ------------- K4: num/den -> zbuf -------------
__global__ __launch_bounds__(256)
void k4_attn(const float* __restrict__ qp, const float* __restrict__ kvs,
             const float* __restrict__ ksum, float* __restrict__ zbuf) {
  __shared__ float kvsl[120 * 68];
  __shared__ float ksl[120];
  __shared__ float qpl[32 * 120];
  const int t = threadIdx.x;
  const int n0 = blockIdx.x * 32;
#pragma unroll
  for (int l = 0; l < 30; ++l) {
    const int f = l * 256 + t;           // 7680
    const int hm = f >> 6, d = f & 63;
    kvsl[hm * 68 + d] = kvs[f];
  }
  if (t < 120) ksl[t] = ksum[t];
#pragma unroll
  for (int l = 0; l < 15; ++l) {
    const int f = l * 256 + t;           // 3840
    qpl[f] = qp[(size_t)n0 * 120 + f];
  }
  __syncthreads();
  const int nl = t >> 3, dg = t & 7, d0 = dg * 8;
  const float* qrow = &qpl[nl * 120];
  float den[4] = {0, 0, 0, 0};
  for (int m = 0; m < 30; ++m) {
#pragma unroll
    for (int hh = 0; hh < 4; ++hh) den[hh] = fmaf(qrow[hh * 30 + m], ksl[hh * 30 + m], den[hh]);
  }
  float acc[4][8] = {};
  for (int m = 0; m < 30; ++m) {
#pragma unroll
    for (int hh = 0; hh < 4; ++hh) {
      const float qv = qrow[hh * 30 + m];
      const float* kr = &kvsl[(hh * 30 + m) * 68 + d0];
      const float4 ka = *(const float4*)kr;
      const float4 kb = *(const float4*)(kr + 4);
      fma4(&acc[hh][0], qv, ka);
      fma4(&acc[hh][4], qv, kb);
    }
  }
  const size_t n = n0 + nl;
#pragma unroll
  for (int hh = 0; hh < 4; ++hh) {
    const float inv = 1.0f / den[hh];
    float4 o1 = make_float4(acc[hh][0] * inv, acc[hh][1] * inv, acc[hh][2] * inv, acc[hh][3] * inv);
    float4 o2 = make_float4(acc[hh][4] * inv, acc[hh][5] * inv, acc[hh][6] * inv, acc[hh][7] * inv);
    *(float4*)(zbuf + n * 256 + hh * 64 + d0) = o1;
    *(float4*)(zbuf + n * 256 + hh * 64 + d0 + 4) = o2;
  }
}

// ------------- K5: degree counts (int4 vectorized) -------------
__global__ __launch_bounds__(256)
void k5_deg(const int* __restrict__ ei, int* __restrict__ dini, int* __restrict__ douti) {
  const int q = blockIdx.x * 256 + threadIdx.x;
  if (q >= EE / 4) return;
  const int4 r4 = *(const int4*)(ei + q * 4);
  const int4 c4 = *(const int4*)(ei + EE + q * 4);
  atomicAdd(&dini[c4.x], 1); atomicAdd(&dini[c4.y], 1);
  atomicAdd(&dini[c4.z], 1); atomicAdd(&dini[c4.w], 1);
  atomicAdd(&douti[r4.x], 1); atomicAdd(&douti[r4.y], 1);
  atomicAdd(&douti[r4.z], 1); atomicAdd(&douti[r4.w], 1);
}

// ------------- K6a: exclusive scan of in-degrees (1024 threads, int4) -------------
__global__ __launch_bounds__(1024)
void k6a_scan(const int* __restrict__ cnt, int* __restrict__ off) {
  __shared__ int s[1024];
  const int t = threadIdx.x;
  int4 v[5];
  int sum = 0;
  const int4* p4 = (const int4*)(cnt + t * 20);
#pragma unroll
  for (int i = 0; i < 5; ++i) {
    v[i] = p4[i];
    sum += v[i].x + v[i].y + v[i].z + v[i].w;
  }
  s[t] = sum;
  __syncthreads();
  for (int o = 1; o < 1024; o <<= 1) {
    const int add = (t >= o) ? s[t - o] : 0;
    __syncthreads();
    s[t] += add;
    __syncthreads();
  }
  int run = (t == 0) ? 0 : s[t - 1];
  if (t == 0) off[0] = 0;
  const int base = t * 20;
#pragma unroll
  for (int i = 0; i < 5; ++i) {
    const int vals[4] = {v[i].x, v[i].y, v[i].z, v[i].w};
#pragma unroll
    for (int j = 0; j < 4; ++j) {
      const int idx = base + i * 4 + j;
      if (idx < NN) { run += vals[j]; off[idx + 1] = run; }
    }
  }
}

// ------------- K6b: fill CSR (rows bucketed by col) -------------
__global__ __launch_bounds__(256)
void k6b_fill(const int* __restrict__ ei, const int* __restrict__ coff,
              int* __restrict__ cursor, int* __restrict__ crow) {
  const int e = blockIdx.x * 256 + threadIdx.x;
  const int r = ei[e], c = ei[EE + e];
  const int pos = atomicAdd(&cursor[c], 1);
  crow[coff[c] + pos] = r;
}

// ------------- K6c: rw[n] = rsqrt(out-degree) -------------
__global__ __launch_bounds__(256)
void k6c_rw(const int* __restrict__ douti, float* __restrict__ rw) {
  const int n = blockIdx.x * 256 + threadIdx.x;
  if (n < NN) rw[n] = rsqrtf((float)douti[n]);
}

// ------------- K7g: gather -> aggh (f16, write-only); wave per node -------------
__global__ __launch_bounds__(256)
void k7g_gather(const int* __restrict__ coff, const int* __restrict__ crow,
                const float* __restrict__ rw, const _Float16* __restrict__ vh,
                _Float16* __restrict__ aggh) {
  const int node = blockIdx.x * 4 + (threadIdx.x >> 6);
  const int lane = threadIdx.x & 63;
  const int o0 = coff[node], o1 = coff[node + 1];
  float a0 = 0.f, a1 = 0.f, a2 = 0.f, a3 = 0.f;
  if (o1 > o0) {
    int e = o0;
    for (; e + 8 <= o1; e += 8) {
      int rr[8];
#pragma unroll
      for (int u = 0; u < 8; ++u) rr[u] = crow[e + u];
      float ww[8];
#pragma unroll
      for (int u = 0; u < 8; ++u) ww[u] = rw[rr[u]];
#pragma unroll
      for (int u = 0; u < 8; ++u) {
        const f16x4 vv = *(const f16x4*)(vh + (size_t)rr[u] * 256 + lane * 4);
        a0 = fmaf(ww[u], (float)vv[0], a0);
        a1 = fmaf(ww[u], (float)vv[1], a1);
        a2 = fmaf(ww[u], (float)vv[2], a2);
        a3 = fmaf(ww[u], (float)vv[3], a3);
      }
    }
    for (; e < o1; ++e) {
      const int r = crow[e];
      const float wr = rw[r];
      const f16x4 vv = *(const f16x4*)(vh + (size_t)r * 256 + lane * 4);
      a0 = fmaf(wr, (float)vv[0], a0);
      a1 = fmaf(wr, (float)vv[1], a1);
      a2 = fmaf(wr, (float)vv[2], a2);
      a3 = fmaf(wr, (float)vv[3], a3);
    }
    const float rin = rsqrtf((float)(o1 - o0));
    a0 *= rin; a1 *= rin; a2 *= rin; a3 *= rin;
  }
  f16x4 st;
  st[0] = (_Float16)a0; st[1] = (_Float16)a1;
  st[2] = (_Float16)a2; st[3] = (_Float16)a3;
  *(f16x4*)(aggh + (size_t)node * 256 + lane * 4) = st;
}

// =====================================================================
// K8m: out = (zbuf + sg*aggh) @ Wo^T + bo via MFMA (3-term f16 split).
// 157 blocks x 8 waves x 16 rows; WoF hi/lo (64 KB) staged.
// =====================================================================
__global__ __launch_bounds__(512, 4)
void k8m_out(const float* __restrict__ zbuf, const _Float16* __restrict__ aggh,
             const _Float16* __restrict__ WoFh, const _Float16* __restrict__ WoFl,
             const float* __restrict__ bo, const float* __restrict__ bp,
             float* __restrict__ out) {
  __shared__ __align__(16) _Float16 blds[8 * 4096];   // 64 KB: 0-3 hi, 4-7 lo
  const int t = threadIdx.x;
  const int wid = t >> 6, lane = t & 63;
  const int g = lane >> 4, cl = lane & 15;
  const int rbase = blockIdx.x * 128 + wid * 16;
  int arow = rbase + cl; if (arow > NN - 1) arow = NN - 1;
#pragma unroll
  for (int s = 0; s < 4; ++s) {
    gload16(WoFh + (size_t)s * 4096 + t * 8, &blds[(s * 512 + t) * 8]);
    gload16(WoFl + (size_t)s * 4096 + t * 8, &blds[((s + 4) * 512 + t) * 8]);
  }
  float sgv[4];
#pragma unroll
  for (int hh = 0; hh < 4; ++hh) sgv[hh] = 1.f / (1.f + expf(-bp[hh]));
  const float* zr = zbuf + (size_t)arow * 256;
  const _Float16* ar = aggh + (size_t)arow * 256;
  f16x8 Ah[8], Al[8];
#pragma unroll
  for (int kt = 0; kt < 8; ++kt) {
    const float4 z0 = *(const float4*)(zr + kt * 32 + g * 8);
    const float4 z1 = *(const float4*)(zr + kt * 32 + g * 8 + 4);
    const f16x4 g0 = *(const f16x4*)(ar + kt * 32 + g * 8);
    const f16x4 g1 = *(const f16x4*)(ar + kt * 32 + g * 8 + 4);
    const float sg = sgv[kt >> 1];
    const float ff[8] = {
        z0.x + sg * (float)g0[0], z0.y + sg * (float)g0[1],
        z0.z + sg * (float)g0[2], z0.w + sg * (float)g0[3],
        z1.x + sg * (float)g1[0], z1.y + sg * (float)g1[1],
        z1.z + sg * (float)g1[2], z1.w + sg * (float)g1[3]};
    union { _Float16 h[8]; f16x8 v; } hu, lu;
#pragma unroll
    for (int j = 0; j < 8; ++j) {
      const _Float16 hb = (_Float16)ff[j];
      hu.h[j] = hb;
      lu.h[j] = (_Float16)(ff[j] - (float)hb);
    }
    Ah[kt] = hu.v; Al[kt] = lu.v;
  }
  __syncthreads();
  f32x4 acc[4];
#pragma unroll
  for (int s = 0; s < 4; ++s) acc[s] = (f32x4){0.f, 0.f, 0.f, 0.f};
#pragma unroll
  for (int kt = 0; kt < 8; ++kt) {
#pragma unroll
    for (int s = 0; s < 4; ++s) {
      const f16x8 bh = *(const f16x8*)&blds[s * 4096 + kt * 512 + lane * 8];
      const f16x8 bl = *(const f16x8*)&blds[(s + 4) * 4096 + kt * 512 + lane * 8];
      acc[s] = __builtin_amdgcn_mfma_f32_16x16x32_f16(Ah[kt], bh, acc[s], 0, 0, 0);
      acc[s] = __builtin_amdgcn_mfma_f32_16x16x32_f16(Ah[kt], bl, acc[s], 0, 0, 0);
      acc[s] = __builtin_amdgcn_mfma_f32_16x16x32_f16(Al[kt], bh, acc[s], 0, 0, 0);
    }
  }
#pragma unroll
  for (int s = 0; s < 4; ++s) {
    const float bb = bo[s * 16 + cl];
#pragma unroll
    for (int j = 0; j < 4; ++j) {
      const int r = rbase + 4 * g + j;
      if (r < NN) out[(size_t)r * 64 + s * 16 + cl] = acc[s][j] + bb;
    }
  }
}

extern "C" void kernel_launch(void* const* d_in, const int* in_sizes, int n_in,
                              void* d_out, int out_size, void* d_ws, size_t ws_size,
                              hipStream_t stream) {
  (void)in_sizes; (void)n_in; (void)out_size; (void)ws_size;
  const float* z    = (const float*)d_in[0];
  const float* feat = (const float*)d_in[1];
  const int*   ei   = (const int*)d_in[2];
  const float* tau  = (const float*)d_in[3];
  const float* Wq_w = (const float*)d_in[4];
  const float* Wq_b = (const float*)d_in[5];
  const float* Wk_w = (const float*)d_in[6];
  const float* Wk_b = (const float*)d_in[7];
  const float* Wv_w = (const float*)d_in[8];
  const float* Wv_b = (const float*)d_in[9];
  const float* Wo_w = (const float*)d_in[10];
  const float* Wo_b = (const float*)d_in[11];
  const float* bp   = (const float*)d_in[12];
  const float* proj = (const float*)d_in[13];
  float* out = (float*)d_out;

  char* p = (char*)d_ws;
  auto alloc = [&](size_t bytes) { char* r = p; p += (bytes + 255) & ~(size_t)255; return r; };
  _Float16* Wf    = (_Float16*)alloc((size_t)256 * 1024 * 2);
  _Float16* WoFh  = (_Float16*)alloc((size_t)64 * 256 * 2);
  _Float16* WoFl  = (_Float16*)alloc((size_t)64 * 256 * 2);
  float*    bbig  = (float*)alloc(1024 * 4);
  _Float16* vh    = (_Float16*)alloc((size_t)NN * 256 * 2);
  _Float16* aggh  = (_Float16*)alloc((size_t)NN * 256 * 2);
  float*    qp    = (float*)alloc((size_t)NN * 120 * 4);
  float*    kbuf  = (float*)alloc((size_t)NN * 120 * 4);
  float*    zbuf  = (float*)alloc((size_t)NN * 256 * 4);
  float*    partial = (float*)alloc((size_t)4 * NCH * 1952 * 4);
  float*    kvs   = (float*)alloc(7680 * 4);
  float*    ksum  = (float*)alloc(120 * 4);
  float*    rw    = (float*)alloc((size_t)NN * 4);
  // ---- contiguous zero-region ----
  char* z0 = p;
  unsigned* kmaxU = (unsigned*)alloc(16);
  int*      dini  = (int*)alloc((size_t)20480 * 4);   // padded for int4 scan
  int*      douti = (int*)alloc((size_t)NN * 4);
  int*      cursor= (int*)alloc((size_t)NN * 4);
  char* z1 = p;
  int*      coff  = (int*)alloc((size_t)(NN + 1) * 4);
  int*      crow  = (int*)alloc((size_t)EE * 4);

  hipMemsetAsync(z0, 0, (size_t)(z1 - z0), stream);

  k0_build<<<1024, 256, 0, stream>>>(Wq_w, Wk_w, Wv_w, Wq_b, Wk_b, Wv_b, proj, tau, Wf, bbig);
  k0b_wo<<<64, 256, 0, stream>>>(Wo_w, WoFh, WoFl);
  k5_deg<<<(EE / 4 + 255) / 256, 256, 0, stream>>>(ei, dini, douti);
  k6a_scan<<<1, 1024, 0, stream>>>(dini, coff);
  k6b_fill<<<EE / 256, 256, 0, stream>>>(ei, coff, cursor, crow);
  k6c_rw<<<(NN + 255) / 256, 256, 0, stream>>>(douti, rw);
  k1_all<<<dim3(157, 6), 512, 0, stream>>>(feat, z, Wf, bbig, tau, qp, kbuf, vh, kmaxU);
  k7g_gather<<<NN / 4, 256, 0, stream>>>(coff, crow, rw, vh, aggh);
  k3_kvs<<<dim3(NCH, 4), 256, 0, stream>>>(kbuf, vh, kmaxU, partial);
  k3b_reduce<<<(4 * 1952 + 255) / 256, 256, 0, stream>>>(partial, kvs, ksum);
  k4_attn<<<NN / 32, 256, 0, stream>>>(qp, kvs, ksum, zbuf);
  k8m_out<<<157, 512, 0, stream>>>(zbuf, aggh, WoFh, WoFl, Wo_b, bp, out);
}

// Round 11
// 257.200 us; speedup vs baseline: 1.2925x; 1.0907x over previous
//
#include <hip/hip_runtime.h>

#define NN 20000
#define EE 320000
#define RATIO_F 0.18257418583505536f   // 1/sqrt(30)
#define EPS_F 1e-6f
#define SCALE_D4 0.35355339059327373f  // 64^-0.25
#define NCH 157                        // ceil(20000/128) k3 chunks

typedef _Float16 f16x8 __attribute__((ext_vector_type(8)));
typedef _Float16 f16x4 __attribute__((ext_vector_type(4)));
typedef float f32x4 __attribute__((ext_vector_type(4)));

__device__ __forceinline__ unsigned fenc(float x) {
  unsigned u = __float_as_uint(x);
  return (u & 0x80000000u) ? ~u : (u | 0x80000000u);
}
__device__ __forceinline__ float fdec(unsigned u) {
  return (u & 0x80000000u) ? __uint_as_float(u & 0x7FFFFFFFu) : __uint_as_float(~u);
}
__device__ __forceinline__ void fma4(float* a, float s, float4 b) {
  a[0] = fmaf(s, b.x, a[0]);
  a[1] = fmaf(s, b.y, a[1]);
  a[2] = fmaf(s, b.z, a[2]);
  a[3] = fmaf(s, b.w, a[3]);
}
// async global->LDS, 16B per lane; LDS dest must be wave-uniform base + lane*16
__device__ __forceinline__ void gload16(const void* g, void* l) {
  __builtin_amdgcn_global_load_lds(
      (const __attribute__((address_space(1))) unsigned int*)g,
      (__attribute__((address_space(3))) unsigned int*)l, 16, 0, 0);
}

// =====================================================================
// K0 (merged): blocks 0-1023 build fused weight plane Wf + bbig;
// blocks 1024-1087 build Wo hi/lo fragment planes.
// Fragment fi = ct*8+kt (512 f16); lane l=(g*16+cl), elem j holds
// W[k=32*kt+8*g+j][col=ct*16+cl].
// =====================================================================
__global__ __launch_bounds__(256)
void k0_build(const float* __restrict__ Wq, const float* __restrict__ Wk,
              const float* __restrict__ Wv, const float* __restrict__ bq,
              const float* __restrict__ bk, const float* __restrict__ bv,
              const float* __restrict__ proj, const float* __restrict__ tau,
              const float* __restrict__ Wo,
              _Float16* __restrict__ Wf, float* __restrict__ bbig,
              _Float16* __restrict__ WoFh, _Float16* __restrict__ WoFl) {
  const int blk = blockIdx.x;
  const int i = threadIdx.x;   // k index
  const int kt = i >> 5, gg = (i >> 3) & 3, j = i & 7;
  if (blk >= 1024) {           // ---- Wo planes ----
    const int col = blk - 1024;
    const float val = Wo[col * 256 + i];
    const int lane = gg * 16 + (col & 15);
    const size_t off = (size_t)((col >> 4) * 8 + kt) * 512 + lane * 8 + j;
    const _Float16 hb = (_Float16)val;
    WoFh[off] = hb;
    WoFl[off] = (_Float16)(val - (float)hb);
    return;
  }
  const int col = blk;
  const float s = rsqrtf(tau[0]) * SCALE_D4;
  float val = 0.f, bias = 0.f;
  if (col < 256) {
    val = Wq[col * 256 + i]; bias = bq[col];
  } else if (col < 512) {
    const int c = col - 256;
    val = Wk[c * 256 + i]; bias = bk[c];
  } else if (col < 768) {
    const int c = col - 512;
    val = Wv[c * 256 + i]; bias = bv[c];
  } else {
    const int rr = col - 768;
    const int grp = rr >> 7;             // 0 = q, 1 = k
    const int h = (rr >> 5) & 3, m = rr & 31;
    if (m < 30) {
      const float* W = grp ? Wk : Wq;
      const float* bb = grp ? bk : bq;
      float a = 0.f, ba = 0.f;
#pragma unroll 8
      for (int d = 0; d < 64; ++d) {
        const float pr = proj[m * 64 + d];
        a  = fmaf(pr, W[(h * 64 + d) * 256 + i], a);
        ba = fmaf(pr, bb[h * 64 + d], ba);
      }
      val = s * a; bias = s * ba;
    }
  }
  const int lane = gg * 16 + (col & 15);
  const size_t off = (size_t)((col >> 4) * 8 + kt) * 512 + lane * 8 + j;
  Wf[off] = (_Float16)val;
  if (i == 0) bbig[col] = bias;
}

// ---- convert 4 kt worth of raw float4 pairs -> f16 hi + f16 residual ----
__device__ __forceinline__ void cvt_half(const float4* raw, f16x8* Ah, f16x8* Al) {
#pragma unroll
  for (int kt = 0; kt < 4; ++kt) {
    const float ff[8] = {raw[kt*2].x, raw[kt*2].y, raw[kt*2].z, raw[kt*2].w,
                         raw[kt*2+1].x, raw[kt*2+1].y, raw[kt*2+1].z, raw[kt*2+1].w};
    union { _Float16 h[8]; f16x8 v; } hu, lu;
#pragma unroll
    for (int j = 0; j < 8; ++j) {
      const _Float16 hb = (_Float16)ff[j];
      hu.h[j] = hb;
      lu.h[j] = (_Float16)(ff[j] - (float)hb);
    }
    Ah[kt] = hu.v; Al[kt] = lu.v;
  }
}

// ---- ct index for slice slot s ----
__device__ __forceinline__ int ct_of(int s, int isv, int h, int y) {
  if (isv) return 32 + (y - 4) * 8 + s;
  if (s < 4)  return h * 4 + s;
  if (s < 8)  return 16 + h * 4 + (s - 4);
  if (s < 10) return 48 + 2 * h + (s - 8);
  return 56 + 2 * h + (s - 10);
}

// =====================================================================
// K1: grid (157, 6) x 512 thr (8 waves x 16 rows). K-split pipeline.
// (R10 structure unchanged; qp now stored f16.)
// =====================================================================
__global__ __launch_bounds__(512, 4)
void k1_all(const float* __restrict__ feat, const float* __restrict__ zin,
            const _Float16* __restrict__ Wf, const float* __restrict__ bbig,
            const float* __restrict__ tau,
            _Float16* __restrict__ qph, float* __restrict__ kbuf,
            _Float16* __restrict__ vh, unsigned* __restrict__ kmaxU) {
  __shared__ __align__(16) _Float16 blds[12 * 2048];   // 48 KB
  const int t = threadIdx.x;
  const int wid = t >> 6, lane = t & 63;
  const int g = lane >> 4, cl = lane & 15;
  const int y = blockIdx.y;
  const int h = y & 3;
  const int rbase = blockIdx.x * 128 + wid * 16;
  int arow = rbase + cl; if (arow > NN - 1) arow = NN - 1;

  if (y < 4) {
    const float* arp = feat + (size_t)arow * 256;
#pragma unroll
    for (int r = 0; r < 6; ++r) {
      const int idx = r * 4096 + t * 8;
      const int s = idx >> 11, wi = idx & 2047;
      gload16(Wf + (size_t)ct_of(s, 0, h, y) * 4096 + wi, &blds[idx]);
    }
    float4 raw[8];
#pragma unroll
    for (int l = 0; l < 4; ++l) {
      raw[l * 2]     = *(const float4*)(arp + l * 32 + g * 8);
      raw[l * 2 + 1] = *(const float4*)(arp + l * 32 + g * 8 + 4);
    }
    f16x8 Ah[4], Al[4];
    cvt_half(raw, Ah, Al);
    __syncthreads();
#pragma unroll
    for (int l = 0; l < 4; ++l) {
      raw[l * 2]     = *(const float4*)(arp + (l + 4) * 32 + g * 8);
      raw[l * 2 + 1] = *(const float4*)(arp + (l + 4) * 32 + g * 8 + 4);
    }
    f32x4 acc[12];
#pragma unroll
    for (int s = 0; s < 12; ++s) acc[s] = (f32x4){0.f, 0.f, 0.f, 0.f};
#pragma unroll
    for (int ktl = 0; ktl < 4; ++ktl) {
#pragma unroll
      for (int s = 0; s < 12; ++s) {
        const f16x8 b = *(const f16x8*)&blds[s * 2048 + ktl * 512 + lane * 8];
        acc[s] = __builtin_amdgcn_mfma_f32_16x16x32_f16(Ah[ktl], b, acc[s], 0, 0, 0);
        acc[s] = __builtin_amdgcn_mfma_f32_16x16x32_f16(Al[ktl], b, acc[s], 0, 0, 0);
      }
    }
    __syncthreads();
#pragma unroll
    for (int r = 0; r < 6; ++r) {
      const int idx = r * 4096 + t * 8;
      const int s = idx >> 11, wi = idx & 2047;
      gload16(Wf + (size_t)ct_of(s, 0, h, y) * 4096 + 2048 + wi, &blds[idx]);
    }
    cvt_half(raw, Ah, Al);
    __syncthreads();
#pragma unroll
    for (int ktl = 0; ktl < 4; ++ktl) {
#pragma unroll
      for (int s = 0; s < 12; ++s) {
        const f16x8 b = *(const f16x8*)&blds[s * 2048 + ktl * 512 + lane * 8];
        acc[s] = __builtin_amdgcn_mfma_f32_16x16x32_f16(Ah[ktl], b, acc[s], 0, 0, 0);
        acc[s] = __builtin_amdgcn_mfma_f32_16x16x32_f16(Al[ktl], b, acc[s], 0, 0, 0);
      }
    }
#pragma unroll
    for (int s = 0; s < 12; ++s) {
      const float bb = bbig[ct_of(s, 0, h, y) * 16 + cl];
#pragma unroll
      for (int j = 0; j < 4; ++j) acc[s][j] += bb;
    }
    const float sc = rsqrtf(tau[0]) * SCALE_D4;
    const float h2 = 0.5f * sc * sc;
    float dsq[4], dsk[4];
#pragma unroll
    for (int j = 0; j < 4; ++j) {
      dsq[j] = acc[0][j] * acc[0][j] + acc[1][j] * acc[1][j] +
               acc[2][j] * acc[2][j] + acc[3][j] * acc[3][j];
      dsk[j] = acc[4][j] * acc[4][j] + acc[5][j] * acc[5][j] +
               acc[6][j] * acc[6][j] + acc[7][j] * acc[7][j];
    }
#pragma unroll
    for (int m = 1; m < 16; m <<= 1) {
#pragma unroll
      for (int j = 0; j < 4; ++j) {
        dsq[j] += __shfl_xor(dsq[j], m);
        dsk[j] += __shfl_xor(dsk[j], m);
      }
    }
    {  // xd_q -> qph (f16)
#pragma unroll
      for (int j = 0; j < 4; ++j) {
        const float x0 = acc[8][j], x1 = acc[9][j];
        float mv = fmaxf(x0, (cl < 14) ? x1 : -3.4e38f);
#pragma unroll
        for (int m = 1; m < 16; m <<= 1) mv = fmaxf(mv, __shfl_xor(mv, m));
        const float dg = h2 * dsq[j];
        const int r = rbase + 4 * g + j;
        if (r < NN) {
          _Float16* dst = qph + (size_t)r * 120 + h * 30;
          dst[cl] = (_Float16)(RATIO_F * (expf(x0 - dg - mv) + EPS_F));
          if (cl < 14)
            dst[16 + cl] = (_Float16)(RATIO_F * (expf(x1 - dg - mv) + EPS_F));
        }
      }
    }
    {  // xd_k -> kbuf + global head max
      float wmax = -3.4e38f;
#pragma unroll
      for (int j = 0; j < 4; ++j) {
        const float x0 = acc[10][j], x1 = acc[11][j];
        float mv = fmaxf(x0, (cl < 14) ? x1 : -3.4e38f);
#pragma unroll
        for (int m = 1; m < 16; m <<= 1) mv = fmaxf(mv, __shfl_xor(mv, m));
        wmax = fmaxf(wmax, mv);
        const float dg = h2 * dsk[j];
        const int r = rbase + 4 * g + j;
        if (r < NN) {
          float* dst = kbuf + (size_t)r * 120 + h * 30;
          dst[cl] = x0 - dg;
          if (cl < 14) dst[16 + cl] = x1 - dg;
        }
      }
      wmax = fmaxf(wmax, __shfl_xor(wmax, 16));
      wmax = fmaxf(wmax, __shfl_xor(wmax, 32));
      if (lane == 0) atomicMax(&kmaxU[h], fenc(wmax));
    }
  } else {
    const float* arp = zin + (size_t)arow * 256;
#pragma unroll
    for (int r = 0; r < 4; ++r) {
      const int idx = r * 4096 + t * 8;
      const int s = idx >> 11, wi = idx & 2047;
      gload16(Wf + (size_t)ct_of(s, 1, h, y) * 4096 + wi, &blds[idx]);
    }
    float4 raw[8];
#pragma unroll
    for (int l = 0; l < 4; ++l) {
      raw[l * 2]     = *(const float4*)(arp + l * 32 + g * 8);
      raw[l * 2 + 1] = *(const float4*)(arp + l * 32 + g * 8 + 4);
    }
    f16x8 Ah[4], Al[4];
    cvt_half(raw, Ah, Al);
    __syncthreads();
#pragma unroll
    for (int l = 0; l < 4; ++l) {
      raw[l * 2]     = *(const float4*)(arp + (l + 4) * 32 + g * 8);
      raw[l * 2 + 1] = *(const float4*)(arp + (l + 4) * 32 + g * 8 + 4);
    }
    f32x4 acc[8];
#pragma unroll
    for (int s = 0; s < 8; ++s) acc[s] = (f32x4){0.f, 0.f, 0.f, 0.f};
#pragma unroll
    for (int ktl = 0; ktl < 4; ++ktl) {
#pragma unroll
      for (int s = 0; s < 8; ++s) {
        const f16x8 b = *(const f16x8*)&blds[s * 2048 + ktl * 512 + lane * 8];
        acc[s] = __builtin_amdgcn_mfma_f32_16x16x32_f16(Ah[ktl], b, acc[s], 0, 0, 0);
        acc[s] = __builtin_amdgcn_mfma_f32_16x16x32_f16(Al[ktl], b, acc[s], 0, 0, 0);
      }
    }
    __syncthreads();
#pragma unroll
    for (int r = 0; r < 4; ++r) {
      const int idx = r * 4096 + t * 8;
      const int s = idx >> 11, wi = idx & 2047;
      gload16(Wf + (size_t)ct_of(s, 1, h, y) * 4096 + 2048 + wi, &blds[idx]);
    }
    cvt_half(raw, Ah, Al);
    __syncthreads();
#pragma unroll
    for (int ktl = 0; ktl < 4; ++ktl) {
#pragma unroll
      for (int s = 0; s < 8; ++s) {
        const f16x8 b = *(const f16x8*)&blds[s * 2048 + ktl * 512 + lane * 8];
        acc[s] = __builtin_amdgcn_mfma_f32_16x16x32_f16(Ah[ktl], b, acc[s], 0, 0, 0);
        acc[s] = __builtin_amdgcn_mfma_f32_16x16x32_f16(Al[ktl], b, acc[s], 0, 0, 0);
      }
    }
#pragma unroll
    for (int s = 0; s < 8; ++s) {
      const int ct = ct_of(s, 1, h, y);
      const float bb = bbig[ct * 16 + cl];
      const int colb = (ct - 32) * 16 + cl;
#pragma unroll
      for (int j = 0; j < 4; ++j) {
        const int r = rbase + 4 * g + j;
        if (r < NN) vh[(size_t)r * 256 + colb] = (_Float16)(acc[s][j] + bb);
      }
    }
  }
}

// ------------- K3a: per-chunk partials of kvs/ksum (no atomics) -------------
__global__ __launch_bounds__(256)
void k3_kvs(const float* __restrict__ kbr, const _Float16* __restrict__ vh,
            const unsigned* __restrict__ kmaxU, float* __restrict__ partial) {
  __shared__ float kpch[128 * 32];
  __shared__ float vch[128 * 68];
  const int h = blockIdx.y;
  const int n0 = blockIdx.x * 128;
  const int cnt = min(128, NN - n0);
  const int t = threadIdx.x;
  const float mx = fdec(kmaxU[h]);
  const int m = t >> 3, dg = t & 7, d0 = dg * 8;
#pragma unroll
  for (int l = 0; l < 15; ++l) {
    const int flat = l * 256 + t;
    const int nl = flat / 30, mm = flat - nl * 30;
    kpch[nl * 32 + mm] = (nl < cnt)
        ? RATIO_F * (expf(kbr[(size_t)(n0 + nl) * 120 + h * 30 + mm] - mx) + EPS_F)
        : 0.f;
  }
#pragma unroll
  for (int l = 0; l < 8; ++l) {
    const int f4 = l * 256 + t;
    const int nl = f4 >> 4, dd = (f4 & 15) * 4;
    float4 vv = make_float4(0.f, 0.f, 0.f, 0.f);
    if (nl < cnt) {
      f16x4 u = *(const f16x4*)(vh + (size_t)(n0 + nl) * 256 + h * 64 + dd);
      vv = make_float4((float)u[0], (float)u[1], (float)u[2], (float)u[3]);
    }
    *(float4*)&vch[nl * 68 + dd] = vv;
  }
  __syncthreads();
  float acc[8] = {0, 0, 0, 0, 0, 0, 0, 0};
  float asum = 0.f;
  const int ms = (m < 30) ? m : 0;
  for (int nl = 0; nl < cnt; ++nl) {
    const float kv = kpch[nl * 32 + ms];
    const float4 va = *(const float4*)&vch[nl * 68 + d0];
    const float4 vb = *(const float4*)&vch[nl * 68 + d0 + 4];
    fma4(&acc[0], kv, va);
    fma4(&acc[4], kv, vb);
    asum += kv;
  }
  if (m < 30) {
    float* dst = partial + ((size_t)blockIdx.y * NCH + blockIdx.x) * 1952 + m * 64 + d0;
#pragma unroll
    for (int j = 0; j < 8; ++j) dst[j] = acc[j];
    if (dg == 0)
      partial[((size_t)blockIdx.y * NCH + blockIdx.x) * 1952 + 1920 + m] = asum;
  }
}

// ------------- K3b: reduce partials -> kvs, ksum -------------
__global__ __launch_bounds__(256)
void k3b_reduce(const float* __restrict__ partial, float* __restrict__ kvs,
                float* __restrict__ ksum) {
  const int idx = blockIdx.x * 256 + threadIdx.x;
  if (idx >= 4 * 1952) return;
  const int h = idx / 1952, q = idx - h * 1952;
  float s = 0.f;
  for (int c = 0; c < NCH; ++c)
    s += partial[((size_t)h * NCH + c) * 1952 + q];
  if (q < 1920) kvs[h * 1920 + q] = s;
  else if (q < 1950) ksum[h * 30 + (q - 1920)] = s;
}

// ------------- K4: num/den + sg*agg -> zh (f16) -------------
__global__ __launch_bounds__(256)
void k4_attn(const _Float16* __restrict__ qph, const float* __restrict__ kvs,
             const float* __restrict__ ksum, const _Float16* __restrict__ aggh,
             const float* __restrict__ bp, _Float16* __restrict__ zh) {
  __shared__ float kvsl[120 * 68];
  __shared__ float ksl[120];
  __shared__ float qpl[32 * 120];
  const int t = threadIdx.x;
  const int n0 = blockIdx.x * 32;
#pragma unroll
  for (int l = 0; l < 30; ++l) {
    const int f = l * 256 + t;           // 7680
    const int hm = f >> 6, d = f & 63;
    kvsl[hm * 68 + d] = kvs[f];
  }
  if (t < 120) ksl[t] = ksum[t];
#pragma unroll
  for (int l = 0; l < 15; ++l) {
    const int f = l * 256 + t;           // 3840
    qpl[f] = (float)qph[(size_t)n0 * 120 + f];
  }
  __syncthreads();
  const int nl = t >> 3, dg = t & 7, d0 = dg * 8;
  const float* qrow = &qpl[nl * 120];
  float den[4] = {0, 0, 0, 0};
  for (int m = 0; m < 30; ++m) {
#pragma unroll
    for (int hh = 0; hh < 4; ++hh) den[hh] = fmaf(qrow[hh * 30 + m], ksl[hh * 30 + m], den[hh]);
  }
  float acc[4][8] = {};
  for (int m = 0; m < 30; ++m) {
#pragma unroll
    for (int hh = 0; hh < 4; ++hh) {
      const float qv = qrow[hh * 30 + m];
      const float* kr = &kvsl[(hh * 30 + m) * 68 + d0];
      const float4 ka = *(const float4*)kr;
      const float4 kb = *(const float4*)(kr + 4);
      fma4(&acc[hh][0], qv, ka);
      fma4(&acc[hh][4], qv, kb);
    }
  }
  const size_t n = n0 + nl;
#pragma unroll
  for (int hh = 0; hh < 4; ++hh) {
    const float inv = 1.0f / den[hh];
    const float sg = 1.f / (1.f + expf(-bp[hh]));
    const f16x8 ag = *(const f16x8*)(aggh + n * 256 + hh * 64 + d0);
    f16x8 o;
#pragma unroll
    for (int jj = 0; jj < 8; ++jj)
      o[jj] = (_Float16)(acc[hh][jj] * inv + sg * (float)ag[jj]);
    *(f16x8*)(zh + n * 256 + hh * 64 + d0) = o;
  }
}

// ------------- K5: degree counts (int4 vectorized) -------------
__global__ __launch_bounds__(256)
void k5_deg(const int* __restrict__ ei, int* __restrict__ dini, int* __restrict__ douti) {
  const int q = blockIdx.x * 256 + threadIdx.x;
  if (q >= EE / 4) return;
  const int4 r4 = *(const int4*)(ei + q * 4);
  const int4 c4 = *(const int4*)(ei + EE + q * 4);
  atomicAdd(&dini[c4.x], 1); atomicAdd(&dini[c4.y], 1);
  atomicAdd(&dini[c4.z], 1); atomicAdd(&dini[c4.w], 1);
  atomicAdd(&douti[r4.x], 1); atomicAdd(&douti[r4.y], 1);
  atomicAdd(&douti[r4.z], 1); atomicAdd(&douti[r4.w], 1);
}

// ------------- K6a: exclusive scan of in-degrees (1024 threads, int4) -------------
__global__ __launch_bounds__(1024)
void k6a_scan(const int* __restrict__ cnt, int* __restrict__ off) {
  __shared__ int s[1024];
  const int t = threadIdx.x;
  int4 v[5];
  int sum = 0;
  const int4* p4 = (const int4*)(cnt + t * 20);
#pragma unroll
  for (int i = 0; i < 5; ++i) {
    v[i] = p4[i];
    sum += v[i].x + v[i].y + v[i].z + v[i].w;
  }
  s[t] = sum;
  __syncthreads();
  for (int o = 1; o < 1024; o <<= 1) {
    const int add = (t >= o) ? s[t - o] : 0;
    __syncthreads();
    s[t] += add;
    __syncthreads();
  }
  int run = (t == 0) ? 0 : s[t - 1];
  if (t == 0) off[0] = 0;
  const int base = t * 20;
#pragma unroll
  for (int i = 0; i < 5; ++i) {
    const int vals[4] = {v[i].x, v[i].y, v[i].z, v[i].w};
#pragma unroll
    for (int j = 0; j < 4; ++j) {
      const int idx = base + i * 4 + j;
      if (idx < NN) { run += vals[j]; off[idx + 1] = run; }
    }
  }
}

// ------------- K6bc (merged): fill CSR + rw = rsqrt(out-degree) -------------
__global__ __launch_bounds__(256)
void k6bc(const int* __restrict__ ei, const int* __restrict__ coff,
          int* __restrict__ cursor, int* __restrict__ crow,
          const int* __restrict__ douti, float* __restrict__ rw) {
  const int b = blockIdx.x;
  if (b < EE / 256) {
    const int e = b * 256 + threadIdx.x;
    const int r = ei[e], c = ei[EE + e];
    const int pos = atomicAdd(&cursor[c], 1);
    crow[coff[c] + pos] = r;
  } else {
    const int n = (b - EE / 256) * 256 + threadIdx.x;
    if (n < NN) rw[n] = rsqrtf((float)douti[n]);
  }
}

// ------------- K7g: gather -> aggh (f16, write-only); wave per node -------------
__global__ __launch_bounds__(256)
void k7g_gather(const int* __restrict__ coff, const int* __restrict__ crow,
                const float* __restrict__ rw, const _Float16* __restrict__ vh,
                _Float16* __restrict__ aggh) {
  const int node = blockIdx.x * 4 + (threadIdx.x >> 6);
  const int lane = threadIdx.x & 63;
  const int o0 = coff[node], o1 = coff[node + 1];
  float a0 = 0.f, a1 = 0.f, a2 = 0.f, a3 = 0.f;
  if (o1 > o0) {
    int e = o0;
    for (; e + 8 <= o1; e += 8) {
      int rr[8];
#pragma unroll
      for (int u = 0; u < 8; ++u) rr[u] = crow[e + u];
      float ww[8];
#pragma unroll
      for (int u = 0; u < 8; ++u) ww[u] = rw[rr[u]];
#pragma unroll
      for (int u = 0; u < 8; ++u) {
        const f16x4 vv = *(const f16x4*)(vh + (size_t)rr[u] * 256 + lane * 4);
        a0 = fmaf(ww[u], (float)vv[0], a0);
        a1 = fmaf(ww[u], (float)vv[1], a1);
        a2 = fmaf(ww[u], (float)vv[2], a2);
        a3 = fmaf(ww[u], (float)vv[3], a3);
      }
    }
    for (; e < o1; ++e) {
      const int r = crow[e];
      const float wr = rw[r];
      const f16x4 vv = *(const f16x4*)(vh + (size_t)r * 256 + lane * 4);
      a0 = fmaf(wr, (float)vv[0], a0);
      a1 = fmaf(wr, (float)vv[1], a1);
      a2 = fmaf(wr, (float)vv[2], a2);
      a3 = fmaf(wr, (float)vv[3], a3);
    }
    const float rin = rsqrtf((float)(o1 - o0));
    a0 *= rin; a1 *= rin; a2 *= rin; a3 *= rin;
  }
  f16x4 st;
  st[0] = (_Float16)a0; st[1] = (_Float16)a1;
  st[2] = (_Float16)a2; st[3] = (_Float16)a3;
  *(f16x4*)(aggh + (size_t)node * 256 + lane * 4) = st;
}

// =====================================================================
// K8m: out = zh @ Wo^T + bo via MFMA. A = zh exact f16 -> 2-term (B hi/lo).
// 157 blocks x 8 waves x 16 rows; WoF hi/lo (64 KB) staged.
// =====================================================================
__global__ __launch_bounds__(512, 4)
void k8m_out(const _Float16* __restrict__ zh, const _Float16* __restrict__ WoFh,
             const _Float16* __restrict__ WoFl, const float* __restrict__ bo,
             float* __restrict__ out) {
  __shared__ __align__(16) _Float16 blds[8 * 4096];   // 64 KB: 0-3 hi, 4-7 lo
  const int t = threadIdx.x;
  const int wid = t >> 6, lane = t & 63;
  const int g = lane >> 4, cl = lane & 15;
  const int rbase = blockIdx.x * 128 + wid * 16;
  int arow = rbase + cl; if (arow > NN - 1) arow = NN - 1;
#pragma unroll
  for (int s = 0; s < 4; ++s) {
    gload16(WoFh + (size_t)s * 4096 + t * 8, &blds[(s * 512 + t) * 8]);
    gload16(WoFl + (size_t)s * 4096 + t * 8, &blds[((s + 4) * 512 + t) * 8]);
  }
  const _Float16* zr = zh + (size_t)arow * 256;
  f16x8 Ah[8];
#pragma unroll
  for (int kt = 0; kt < 8; ++kt)
    Ah[kt] = *(const f16x8*)(zr + kt * 32 + g * 8);
  __syncthreads();
  f32x4 acc[4];
#pragma unroll
  for (int s = 0; s < 4; ++s) acc[s] = (f32x4){0.f, 0.f, 0.f, 0.f};
#pragma unroll
  for (int kt = 0; kt < 8; ++kt) {
#pragma unroll
    for (int s = 0; s < 4; ++s) {
      const f16x8 bh = *(const f16x8*)&blds[s * 4096 + kt * 512 + lane * 8];
      const f16x8 bl = *(const f16x8*)&blds[(s + 4) * 4096 + kt * 512 + lane * 8];
      acc[s] = __builtin_amdgcn_mfma_f32_16x16x32_f16(Ah[kt], bh, acc[s], 0, 0, 0);
      acc[s] = __builtin_amdgcn_mfma_f32_16x16x32_f16(Ah[kt], bl, acc[s], 0, 0, 0);
    }
  }
#pragma unroll
  for (int s = 0; s < 4; ++s) {
    const float bb = bo[s * 16 + cl];
#pragma unroll
    for (int j = 0; j < 4; ++j) {
      const int r = rbase + 4 * g + j;
      if (r < NN) out[(size_t)r * 64 + s * 16 + cl] = acc[s][j] + bb;
    }
  }
}

extern "C" void kernel_launch(void* const* d_in, const int* in_sizes, int n_in,
                              void* d_out, int out_size, void* d_ws, size_t ws_size,
                              hipStream_t stream) {
  (void)in_sizes; (void)n_in; (void)out_size; (void)ws_size;
  const float* z    = (const float*)d_in[0];
  const float* feat = (const float*)d_in[1];
  const int*   ei   = (const int*)d_in[2];
  const float* tau  = (const float*)d_in[3];
  const float* Wq_w = (const float*)d_in[4];
  const float* Wq_b = (const float*)d_in[5];
  const float* Wk_w = (const float*)d_in[6];
  const float* Wk_b = (const float*)d_in[7];
  const float* Wv_w = (const float*)d_in[8];
  const float* Wv_b = (const float*)d_in[9];
  const float* Wo_w = (const float*)d_in[10];
  const float* Wo_b = (const float*)d_in[11];
  const float* bp   = (const float*)d_in[12];
  const float* proj = (const float*)d_in[13];
  float* out = (float*)d_out;

  char* p = (char*)d_ws;
  auto alloc = [&](size_t bytes) { char* r = p; p += (bytes + 255) & ~(size_t)255; return r; };
  _Float16* Wf    = (_Float16*)alloc((size_t)256 * 1024 * 2);
  _Float16* WoFh  = (_Float16*)alloc((size_t)64 * 256 * 2);
  _Float16* WoFl  = (_Float16*)alloc((size_t)64 * 256 * 2);
  float*    bbig  = (float*)alloc(1024 * 4);
  _Float16* vh    = (_Float16*)alloc((size_t)NN * 256 * 2);
  _Float16* aggh  = (_Float16*)alloc((size_t)NN * 256 * 2);
  _Float16* qph   = (_Float16*)alloc((size_t)NN * 120 * 2);
  float*    kbuf  = (float*)alloc((size_t)NN * 120 * 4);
  _Float16* zh    = (_Float16*)alloc((size_t)NN * 256 * 2);
  float*    partial = (float*)alloc((size_t)4 * NCH * 1952 * 4);
  float*    kvs   = (float*)alloc(7680 * 4);
  float*    ksum  = (float*)alloc(120 * 4);
  float*    rw    = (float*)alloc((size_t)NN * 4);
  // ---- contiguous zero-region ----
  char* z0 = p;
  unsigned* kmaxU = (unsigned*)alloc(16);
  int*      dini  = (int*)alloc((size_t)20480 * 4);   // padded for int4 scan
  int*      douti = (int*)alloc((size_t)NN * 4);
  int*      cursor= (int*)alloc((size_t)NN * 4);
  char* z1 = p;
  int*      coff  = (int*)alloc((size_t)(NN + 1) * 4);
  int*      crow  = (int*)alloc((size_t)EE * 4);

  hipMemsetAsync(z0, 0, (size_t)(z1 - z0), stream);

  k0_build<<<1088, 256, 0, stream>>>(Wq_w, Wk_w, Wv_w, Wq_b, Wk_b, Wv_b, proj,
                                     tau, Wo_w, Wf, bbig, WoFh, WoFl);
  k5_deg<<<(EE / 4 + 255) / 256, 256, 0, stream>>>(ei, dini, douti);
  k6a_scan<<<1, 1024, 0, stream>>>(dini, coff);
  k6bc<<<EE / 256 + (NN + 255) / 256, 256, 0, stream>>>(ei, coff, cursor, crow,
                                                        douti, rw);
  k1_all<<<dim3(157, 6), 512, 0, stream>>>(feat, z, Wf, bbig, tau, qph, kbuf, vh, kmaxU);
  k7g_gather<<<NN / 4, 256, 0, stream>>>(coff, crow, rw, vh, aggh);
  k3_kvs<<<dim3(NCH, 4), 256, 0, stream>>>(kbuf, vh, kmaxU, partial);
  k3b_reduce<<<(4 * 1952 + 255) / 256, 256, 0, stream>>>(partial, kvs, ksum);
  k4_attn<<<NN / 32, 256, 0, stream>>>(qph, kvs, ksum, aggh, bp, zh);
  k8m_out<<<157, 512, 0, stream>>>(zh, WoFh, WoFl, Wo_b, out);
}